// Round 2
// baseline (11487.141 us; speedup 1.0000x reference)
//
#include <hip/hip_runtime.h>
#include <hip/hip_bf16.h>

#define BATCH 64
#define ATOMS 64
#define CIN 3
#define KS 8
#define H 224
#define W 224
#define OH 56
#define OW 56
#define NLAT (BATCH*ATOMS*OH*OW)   // 12,845,056
#define LAM 0.1f
#define ETA 0.1f

__device__ __forceinline__ float softthr(float u) {
    float p = u - LAM;  p = p > 0.f ? p : 0.f;
    float q = -u - LAM; q = q > 0.f ? q : 0.f;
    return p - q;
}

// DT[((c*8+y)*8+x)*64 + m] = D[m,c,y,x]  (m fastest -> coalesced across lanes)
__global__ void prep_dt_kernel(const float* __restrict__ D,
                               float* __restrict__ DT) {
    int idx = blockIdx.x * 256 + threadIdx.x;
    if (idx < CIN*KS*KS*ATOMS) {
        int m = idx & 63;
        int r = idx >> 6;              // c*64 + y*8 + x
        int xk = r & 7, y = (r >> 3) & 7, c = r >> 6;
        DT[idx] = D[((m*CIN + c)*KS + y)*KS + xk];
    }
}

// G[tbl][n][m], tbl = ((cy*3+dp)*3+cx)*3+dq.
// Neighbor p = i + (dp-1)  =>  di = i-p = 1-dp; second kernel row = y + 4*di.
// Class clips (image boundary): cy==1 (i==0): y>=2 ; cy==2 (i==55): y<=5.
__global__ void prep_gram_kernel(const float* __restrict__ DT,
                                 float* __restrict__ G) {
    int tbl = blockIdx.x;              // 0..80
    int dq = tbl % 3, cx = (tbl/3) % 3, dp = (tbl/9) % 3, cy = tbl/27;
    int di = 1 - dp, dj = 1 - dq;
    int ylo = (0 > -4*di) ? 0 : -4*di;
    int yhi = (8 < 8-4*di) ? 8 : 8-4*di;
    if (cy == 1 && ylo < 2) ylo = 2;
    if (cy == 2 && yhi > 6) yhi = 6;
    int xlo = (0 > -4*dj) ? 0 : -4*dj;
    int xhi = (8 < 8-4*dj) ? 8 : 8-4*dj;
    if (cx == 1 && xlo < 2) xlo = 2;
    if (cx == 2 && xhi > 6) xhi = 6;
    int t = threadIdx.x;
    int m = t & 63;
    int nb = (t >> 6) * 16;
    for (int k = 0; k < 16; ++k) {
        int n = nb + k;
        float s = 0.f;
        for (int c = 0; c < CIN; ++c)
            for (int y = ylo; y < yhi; ++y)
                for (int x = xlo; x < xhi; ++x)
                    s += DT[((c*8+y)*8+x)*64 + m] *
                         DT[((c*8+y+4*di)*8 + (x+4*dj))*64 + n];
        G[tbl*4096 + n*64 + m] = s;
    }
}

// b = conv2d(x, D, stride4, pad2); also u = 0.1*b (iteration 1 folded in).
__global__ __launch_bounds__(256) void conv_b_kernel(
        const float* __restrict__ x, const float* __restrict__ DT,
        float* __restrict__ b, float* __restrict__ u) {
    __shared__ float xt[CIN*36*36];    // input patch for an 8x8 output tile
    __shared__ float ot[64*65];        // epilogue remap buffer (+1 pad)
    int blk = blockIdx.x;
    int img = blk / 49, tile = blk % 49;
    int i0 = (tile / 7) * 8, j0 = (tile % 7) * 8;
    int t = threadIdx.x;
    int r0 = 4*i0 - 2, c0 = 4*j0 - 2;
    for (int f = t; f < CIN*36*36; f += 256) {
        int cc = f / 1296, rem = f % 1296;
        int rr = rem / 36, qq = rem % 36;
        int Y = r0 + rr, X = c0 + qq;
        float v = 0.f;
        if (Y >= 0 && Y < H && X >= 0 && X < W)
            v = x[((img*CIN + cc)*H + Y)*W + X];
        xt[f] = v;
    }
    __syncthreads();
    int m = t & 63, grp = t >> 6;      // lanes = m (DT coalesced), 16 pos/thread
    float acc[16];
#pragma unroll
    for (int e = 0; e < 16; ++e) acc[e] = 0.f;
    const float* dtp = DT + m;
    for (int cyx = 0; cyx < CIN*64; ++cyx) {
        float g = dtp[cyx << 6];
        int c = cyx >> 6, y = (cyx >> 3) & 7, xk = cyx & 7;
        int base = c*1296 + y*36 + xk + grp*288;   // rows 2*grp..2*grp+1
#pragma unroll
        for (int e = 0; e < 16; ++e)
            acc[e] += g * xt[base + (e >> 3)*144 + (e & 7)*4];
    }
#pragma unroll
    for (int e = 0; e < 16; ++e) ot[m*65 + grp*16 + e] = acc[e];
    __syncthreads();
#pragma unroll
    for (int e = 0; e < 16; ++e) {     // j-coalesced store
        int flat = e*256 + t;
        int mm = flat >> 6, pos = flat & 63;
        int gi = ((img*ATOMS + mm)*OH + i0 + (pos >> 3))*OW + j0 + (pos & 7);
        float v = ot[mm*65 + pos];
        b[gi] = v;
        u[gi] = ETA * v;
    }
}

// One LCA step: gram = (conv o convT)(a) via 3x3 Gram tables on the lattice;
// u_out = u + 0.1*(b - u - gram + a), a = soft(u) recomputed on the fly.
__global__ __launch_bounds__(256) void lca_iter_kernel(
        const float* __restrict__ b, const float* __restrict__ uin,
        float* __restrict__ uout, const float* __restrict__ G,
        float* __restrict__ out, int last) {
    __shared__ float at[64*100];       // a tile with halo: 64 n x 10 x 10
    __shared__ float ot[64*65];
    int blk = blockIdx.x;
    int img = blk / 49, tile = blk % 49;
    int ti = tile / 7, tj = tile % 7;
    int i0 = ti*8, j0 = tj*8;
    int t = threadIdx.x;
    for (int f = t; f < 6400; f += 256) {
        int n = f / 100, rem = f % 100;
        int p = rem / 10, q = rem % 10;
        int gi = i0 - 1 + p, gj = j0 - 1 + q;
        float v = 0.f;
        if (gi >= 0 && gi < OH && gj >= 0 && gj < OW)
            v = softthr(uin[((img*ATOMS + n)*OH + gi)*OW + gj]);
        at[f] = v;
    }
    __syncthreads();
    int m = t & 63, grp = t >> 6;
    float acc[16];
#pragma unroll
    for (int e = 0; e < 16; ++e) acc[e] = 0.f;
    bool interior = (ti > 0 && ti < 6 && tj > 0 && tj < 6);
    if (interior) {                    // one G table per offset, 16 FMA per load
        for (int dpq = 0; dpq < 9; ++dpq) {
            int dp = dpq / 3, dq = dpq % 3;
            const float* gp = G + (dp*9 + dq)*4096 + m;
            int ab = dp*10 + dq + grp*20;
#pragma unroll 4
            for (int n = 0; n < 64; ++n) {
                float g = gp[n << 6];              // coalesced across lanes
                const float* ap = at + n*100 + ab; // LDS broadcast reads
#pragma unroll
                for (int e = 0; e < 16; ++e)
                    acc[e] += g * ap[(e >> 3)*10 + (e & 7)];
            }
        }
    } else {                           // border tiles: per-position class tables
#pragma unroll 1
        for (int e = 0; e < 16; ++e) {
            int pi = grp*2 + (e >> 3), pj = e & 7;
            int i = i0 + pi, j = j0 + pj;
            int cy = (i == 0) ? 1 : ((i == OH-1) ? 2 : 0);
            int cx = (j == 0) ? 1 : ((j == OW-1) ? 2 : 0);
            float s = 0.f;
            for (int dpq = 0; dpq < 9; ++dpq) {
                int dp = dpq / 3, dq = dpq % 3;
                const float* gp = G + (((cy*3 + dp)*3 + cx)*3 + dq)*4096 + m;
                const float* ap = at + (pi + dp)*10 + pj + dq;
                for (int n = 0; n < 64; ++n)
                    s += gp[n << 6] * ap[n*100];
            }
            acc[e] = s;
        }
    }
#pragma unroll
    for (int e = 0; e < 16; ++e) ot[m*65 + grp*16 + e] = acc[e];
    __syncthreads();
#pragma unroll
    for (int e = 0; e < 16; ++e) {     // j-coalesced elementwise update
        int flat = e*256 + t;
        int mm = flat >> 6, pos = flat & 63;
        int gi = ((img*ATOMS + mm)*OH + i0 + (pos >> 3))*OW + j0 + (pos & 7);
        float uo = uin[gi];
        float gram = ot[mm*65 + pos];
        float un = uo + ETA * (b[gi] - uo - gram + softthr(uo));
        if (last) out[gi] = softthr(un);
        else      uout[gi] = un;
    }
}

extern "C" void kernel_launch(void* const* d_in, const int* in_sizes, int n_in,
                              void* d_out, int out_size, void* d_ws, size_t ws_size,
                              hipStream_t stream) {
    const float* x = (const float*)d_in[0];
    const float* D = (const float*)d_in[1];
    float* out = (float*)d_out;
    float* ws = (float*)d_ws;
    float* b  = ws;                    // 12,845,056 f32
    float* u0 = b  + NLAT;             // 12,845,056 f32
    float* u1 = u0 + NLAT;             // 12,845,056 f32 (ping-pong: halo race)
    float* DT = u1 + NLAT;             // 12,288 f32
    float* G  = DT + CIN*KS*KS*ATOMS;  // 331,776 f32
    prep_dt_kernel<<<48, 256, 0, stream>>>(D, DT);
    prep_gram_kernel<<<81, 256, 0, stream>>>(DT, G);
    conv_b_kernel<<<BATCH*49, 256, 0, stream>>>(x, DT, b, u0);
    float* uin = u0; float* uo2 = u1;
    for (int it = 0; it < 9; ++it) {   // iterations 2..10 (iter 1 folded above)
        int last = (it == 8);
        lca_iter_kernel<<<BATCH*49, 256, 0, stream>>>(b, uin, uo2, G, out, last);
        float* tmp = uin; uin = uo2; uo2 = tmp;
    }
}

// Round 3
// 5795.768 us; speedup vs baseline: 1.9820x; 1.9820x over previous
//
#include <hip/hip_runtime.h>

#define BATCH 64
#define ATOMS 64
#define CIN 3
#define KS 8
#define H 224
#define W 224
#define OH 56
#define OW 56
#define NLAT (BATCH*ATOMS*OH*OW)   // 12,845,056
#define LAM 0.1f
#define ETA 0.1f

typedef __attribute__((ext_vector_type(8)))  __bf16 bf16x8;
typedef __attribute__((ext_vector_type(16))) float  floatx16;

union FragU { uint4 u; bf16x8 v; };

__device__ __forceinline__ float softthr(float u) {
    float p = u - LAM;  p = p > 0.f ? p : 0.f;
    float q = -u - LAM; q = q > 0.f ? q : 0.f;
    return p - q;
}
__device__ __forceinline__ unsigned short f2bf(float f) {   // RNE
    union { float f; unsigned int u; } c; c.f = f;
    unsigned int r = c.u + 0x7fffu + ((c.u >> 16) & 1u);
    return (unsigned short)(r >> 16);
}
__device__ __forceinline__ float bf2f(unsigned short h) {
    union { unsigned int u; float f; } c; c.u = ((unsigned int)h) << 16;
    return c.f;
}

// DT[((c*8+y)*8+x)*64 + m] = D[m,c,y,x]
__global__ void prep_dt_kernel(const float* __restrict__ D,
                               float* __restrict__ DT) {
    int idx = blockIdx.x * 256 + threadIdx.x;
    if (idx < CIN*KS*KS*ATOMS) {
        int m = idx & 63;
        int r = idx >> 6;
        int xk = r & 7, y = (r >> 3) & 7, c = r >> 6;
        DT[idx] = D[((m*CIN + c)*KS + y)*KS + xk];
    }
}

// 9 table-sets (inclusion-exclusion for boundary classes), 9 dpq each.
// tbl: 0=T0(all) 1=-dY1 2=-dY2 3=-dX1 4=-dX2 5=+dC11 6=+dC12 7=+dC21 8=+dC22
// di = 1-dp; second kernel row = y + 4*di. Clips: Y1 removes y in [0,2),
// Y2 removes y in [6,8) (image-boundary rows at i==0 / i==55).
__global__ void prep_gram_kernel(const float* __restrict__ DT,
                                 float* __restrict__ G) {
    int blk = blockIdx.x;              // tbl*9 + dpq
    int tbl = blk / 9, dpq = blk % 9;
    int dp = dpq / 3, dq = dpq % 3;
    int di = 1 - dp, dj = 1 - dq;
    int ylo = (0 > -4*di) ? 0 : -4*di;
    int yhi = (8 < 8-4*di) ? 8 : 8-4*di;
    int xlo = (0 > -4*dj) ? 0 : -4*dj;
    int xhi = (8 < 8-4*dj) ? 8 : 8-4*dj;
    if (tbl==1 || tbl==5 || tbl==6) { if (yhi > 2) yhi = 2; }
    if (tbl==2 || tbl==7 || tbl==8) { if (ylo < 6) ylo = 6; }
    if (tbl==3 || tbl==5 || tbl==7) { if (xhi > 2) xhi = 2; }
    if (tbl==4 || tbl==6 || tbl==8) { if (xlo < 6) xlo = 6; }
    float sign = (tbl >= 1 && tbl <= 4) ? -1.f : 1.f;
    int t = threadIdx.x;
    int m = t & 63;
    int nb = (t >> 6) * 16;
    for (int k = 0; k < 16; ++k) {
        int n = nb + k;
        float s = 0.f;
        for (int c = 0; c < CIN; ++c)
            for (int y = ylo; y < yhi; ++y)
                for (int x = xlo; x < xhi; ++x)
                    s += DT[((c*8+y)*8+x)*64 + m] *
                         DT[((c*8+y+4*di)*8 + (x+4*dj))*64 + n];
        G[blk*4096 + n*64 + m] = sign * s;
    }
}

// Pack G into MFMA A-operand layout, split bf16 hi/lo.
// uint4 index g = (((tbl*9+dpq)*2+mhalf)*4+kstep)*64 + lane; 8 bf16 per lane.
// A[m][k=n]: m = mhalf*32+(lane&31), n = kstep*16+(lane>>5)*8+j.
__global__ void prep_packg_kernel(const float* __restrict__ G,
                                  unsigned short* __restrict__ GAh,
                                  unsigned short* __restrict__ GAl) {
    int g = blockIdx.x * 256 + threadIdx.x;      // 162*256 = 41472 groups
    int lane = g & 63;
    int r = g >> 6;
    int kstep = r & 3; r >>= 2;
    int mhalf = r & 1; int td = r >> 1;          // tbl*9+dpq
    int m = mhalf*32 + (lane & 31);
    int n = kstep*16 + (lane >> 5)*8;
    const float* src = G + td*4096 + n*64 + m;
#pragma unroll
    for (int j = 0; j < 8; ++j) {
        float v = src[j*64];
        unsigned short h = f2bf(v);
        GAh[g*8 + j] = h;
        GAl[g*8 + j] = f2bf(v - bf2f(h));
    }
}

// Pack D into MFMA A-layout for conv_b: K=192, k = c*64+y*8+x.
__global__ void prep_packd_kernel(const float* __restrict__ D,
                                  unsigned short* __restrict__ DAh,
                                  unsigned short* __restrict__ DAl) {
    int g = blockIdx.x * 256 + threadIdx.x;      // 6*256 = 1536 groups
    if (g >= 1536) return;
    int lane = g & 63;
    int r = g >> 6;                              // 0..23
    int kstep = r % 12, mhalf = r / 12;
    int m = mhalf*32 + (lane & 31);
    int k0 = kstep*16 + (lane >> 5)*8;
#pragma unroll
    for (int j = 0; j < 8; ++j) {
        float v = D[m*192 + k0 + j];
        unsigned short h = f2bf(v);
        DAh[g*8 + j] = h;
        DAl[g*8 + j] = f2bf(v - bf2f(h));
    }
}

// b = conv2d(x, D, stride4, pad2) via split-bf16 MFMA; u = 0.1*b folded in.
__global__ __launch_bounds__(256) void conv_b_kernel(
        const float* __restrict__ x,
        const unsigned short* __restrict__ DAh,
        const unsigned short* __restrict__ DAl,
        float* __restrict__ b, float* __restrict__ u) {
    __shared__ __align__(16) unsigned short xth[CIN*36*36];
    __shared__ __align__(16) unsigned short xtl[CIN*36*36];
    __shared__ float ot[64*65];
    int blk = blockIdx.x;
    int img = blk / 49, tile = blk % 49;
    int i0 = (tile / 7) * 8, j0 = (tile % 7) * 8;
    int t = threadIdx.x;
    int r0 = 4*i0 - 2, c0 = 4*j0 - 2;
    for (int f = t; f < CIN*36*36; f += 256) {
        int cc = f / 1296, rem = f % 1296;
        int rr = rem / 36, qq = rem % 36;
        int Y = r0 + rr, X = c0 + qq;
        float v = 0.f;
        if (Y >= 0 && Y < H && X >= 0 && X < W)
            v = x[((img*CIN + cc)*H + Y)*W + X];
        unsigned short h = f2bf(v);
        xth[f] = h;
        xtl[f] = f2bf(v - bf2f(h));
    }
    __syncthreads();
    int lane = t & 63, wave = t >> 6;
    int mhalf = wave & 1, poshalf = wave >> 1;
    int pos = poshalf*32 + (lane & 31), pi = pos >> 3, pj = pos & 7;
    int khalf = lane >> 5;
    floatx16 acc;
#pragma unroll
    for (int i = 0; i < 16; ++i) acc[i] = 0.f;
    const uint4* Ah4 = (const uint4*)DAh;
    const uint4* Al4 = (const uint4*)DAl;
#pragma unroll 3
    for (int kstep = 0; kstep < 12; ++kstep) {
        int k0 = kstep*16 + khalf*8;
        int cc = k0 >> 6, yy = (k0 >> 3) & 7;
        int boff = cc*1296 + (4*pi + yy)*36 + 4*pj;   // %4==0 -> 8B aligned
        FragU ah, al, bh, bl;
        ah.u = Ah4[(mhalf*12 + kstep)*64 + lane];
        al.u = Al4[(mhalf*12 + kstep)*64 + lane];
        const uint2* ph = (const uint2*)(xth + boff);
        uint2 h0 = ph[0], h1 = ph[1];
        bh.u = make_uint4(h0.x, h0.y, h1.x, h1.y);
        const uint2* pl = (const uint2*)(xtl + boff);
        uint2 l0 = pl[0], l1 = pl[1];
        bl.u = make_uint4(l0.x, l0.y, l1.x, l1.y);
        acc = __builtin_amdgcn_mfma_f32_32x32x16_bf16(ah.v, bh.v, acc, 0, 0, 0);
        acc = __builtin_amdgcn_mfma_f32_32x32x16_bf16(ah.v, bl.v, acc, 0, 0, 0);
        acc = __builtin_amdgcn_mfma_f32_32x32x16_bf16(al.v, bh.v, acc, 0, 0, 0);
    }
#pragma unroll
    for (int r16 = 0; r16 < 16; ++r16) {   // C layout: col=lane&31,
        int row = (r16 & 3) + 8*(r16 >> 2) + 4*khalf;  // row=(reg&3)+8*(reg>>2)+4*(lane>>5)
        ot[(mhalf*32 + row)*65 + pos] = acc[r16];
    }
    __syncthreads();
#pragma unroll
    for (int e = 0; e < 16; ++e) {
        int flat = e*256 + t;
        int mm = flat >> 6, pp = flat & 63;
        int gi = ((img*ATOMS + mm)*OH + i0 + (pp >> 3))*OW + j0 + (pp & 7);
        float v = ot[mm*65 + pp];
        b[gi] = v;
        u[gi] = ETA * v;
    }
}

// One LCA step. gram = sum over active table-sets of (G_tbl * a) as
// 32x32x16 bf16 MFMA GEMMs (split hi/lo, 3 cross terms), with per-lane
// column masks implementing the boundary classes.
__global__ __launch_bounds__(256) void lca_iter_kernel(
        const float* __restrict__ b, const float* __restrict__ uin,
        float* __restrict__ uout,
        const unsigned short* __restrict__ GAh,
        const unsigned short* __restrict__ GAl,
        float* __restrict__ out, int last) {
    __shared__ __align__(16) unsigned short at2h[6400];  // [rc 0..99][n 0..63]
    __shared__ __align__(16) unsigned short at2l[6400];
    __shared__ float rawot[64*101];    // phase1 raw u (padded); reused as ot
    int blk = blockIdx.x;
    int img = blk / 49, tile = blk % 49;
    int ti = tile / 7, tj = tile % 7;
    int i0 = ti*8, j0 = tj*8;
    int t = threadIdx.x;
    for (int f = t; f < 6400; f += 256) {        // coalesced-ish global read
        int n = f / 100, rc = f % 100;
        int p = rc / 10, q = rc % 10;
        int gi = i0 - 1 + p, gj = j0 - 1 + q;
        float v = 0.f;
        if (gi >= 0 && gi < OH && gj >= 0 && gj < OW)
            v = uin[((img*ATOMS + n)*OH + gi)*OW + gj];
        rawot[n*101 + rc] = v;                   // stride 101: conflict-free
    }
    __syncthreads();
    {   // transpose to [rc][n] bf16 (soft-threshold + split)
        int n = t & 63, rcb = t >> 6;
#pragma unroll 5
        for (int k = 0; k < 25; ++k) {
            int rc = rcb*25 + k;
            float a = softthr(rawot[n*101 + rc]);
            unsigned short h = f2bf(a);
            at2h[rc*64 + n] = h;
            at2l[rc*64 + n] = f2bf(a - bf2f(h));
        }
    }
    __syncthreads();
    int lane = t & 63, wave = t >> 6;
    int mhalf = wave & 1, poshalf = wave >> 1;
    int pos = poshalf*32 + (lane & 31), pi = pos >> 3, pj = pos & 7;
    int khalf = lane >> 5;
    floatx16 acc;
#pragma unroll
    for (int i = 0; i < 16; ++i) acc[i] = 0.f;
    const uint4* Gh4 = (const uint4*)GAh;
    const uint4* Gl4 = (const uint4*)GAl;
    int tbls[4]; bool msks[4]; int nt = 0;
    tbls[0] = 0; msks[0] = true; nt = 1;
    if (ti == 0) { tbls[nt] = 1; msks[nt] = (pi == 0); ++nt; }
    if (ti == 6) { tbls[nt] = 2; msks[nt] = (pi == 7); ++nt; }
    if (tj == 0) { tbls[nt] = 3; msks[nt] = (pj == 0); ++nt; }
    if (tj == 6) { tbls[nt] = 4; msks[nt] = (pj == 7); ++nt; }
    if (ti == 0 && tj == 0) { tbls[nt] = 5; msks[nt] = (pi==0 && pj==0); ++nt; }
    if (ti == 0 && tj == 6) { tbls[nt] = 6; msks[nt] = (pi==0 && pj==7); ++nt; }
    if (ti == 6 && tj == 0) { tbls[nt] = 7; msks[nt] = (pi==7 && pj==0); ++nt; }
    if (ti == 6 && tj == 6) { tbls[nt] = 8; msks[nt] = (pi==7 && pj==7); ++nt; }
    for (int it = 0; it < nt; ++it) {            // block-uniform term loop
        int tb = tbls[it]; bool mk = msks[it];
        for (int dpq = 0; dpq < 9; ++dpq) {
            int dp = dpq / 3, dq = dpq - 3*dp;
            int rr = pi + dp, cc = pj + dq;
            int bbase = (rr*10 + cc)*64 + khalf*8;       // bf16 idx, %8==0
            int abase = (((tb*9 + dpq)*2 + mhalf)*4)*64 + lane;
#pragma unroll
            for (int kstep = 0; kstep < 4; ++kstep) {
                FragU ah, al, bh, bl;
                ah.u = Gh4[abase + kstep*64];
                al.u = Gl4[abase + kstep*64];
                bh.u = *(const uint4*)(at2h + bbase + kstep*16);
                bl.u = *(const uint4*)(at2l + bbase + kstep*16);
                if (!mk) { bh.u = make_uint4(0,0,0,0); bl.u = make_uint4(0,0,0,0); }
                acc = __builtin_amdgcn_mfma_f32_32x32x16_bf16(ah.v, bh.v, acc, 0,0,0);
                acc = __builtin_amdgcn_mfma_f32_32x32x16_bf16(ah.v, bl.v, acc, 0,0,0);
                acc = __builtin_amdgcn_mfma_f32_32x32x16_bf16(al.v, bh.v, acc, 0,0,0);
            }
        }
    }
    float* ot = rawot;                 // rawot dead after phase2 -> reuse
#pragma unroll
    for (int r16 = 0; r16 < 16; ++r16) {
        int row = (r16 & 3) + 8*(r16 >> 2) + 4*khalf;
        ot[(mhalf*32 + row)*65 + pos] = acc[r16];
    }
    __syncthreads();
#pragma unroll
    for (int e = 0; e < 16; ++e) {     // j-coalesced fp32 update
        int flat = e*256 + t;
        int mm = flat >> 6, pp = flat & 63;
        int gi = ((img*ATOMS + mm)*OH + i0 + (pp >> 3))*OW + j0 + (pp & 7);
        float uo = uin[gi];
        float gram = ot[mm*65 + pp];
        float un = uo + ETA * (b[gi] - uo - gram + softthr(uo));
        if (last) out[gi] = softthr(un);
        else      uout[gi] = un;
    }
}

extern "C" void kernel_launch(void* const* d_in, const int* in_sizes, int n_in,
                              void* d_out, int out_size, void* d_ws, size_t ws_size,
                              hipStream_t stream) {
    const float* x = (const float*)d_in[0];
    const float* D = (const float*)d_in[1];
    float* out = (float*)d_out;
    float* ws = (float*)d_ws;
    float* b  = ws;                        // NLAT f32
    float* u0 = b  + NLAT;                 // NLAT f32
    float* u1 = u0 + NLAT;                 // NLAT f32
    float* DT = u1 + NLAT;                 // 12288 f32
    float* Gf = DT + 12288;                // 81*4096 = 331776 f32
    unsigned short* GAh = (unsigned short*)(Gf + 331776);   // 331776 bf16
    unsigned short* GAl = GAh + 331776;
    unsigned short* DAh = GAl + 331776;    // 12288 bf16
    unsigned short* DAl = DAh + 12288;
    prep_dt_kernel<<<48, 256, 0, stream>>>(D, DT);
    prep_gram_kernel<<<81, 256, 0, stream>>>(DT, Gf);
    prep_packg_kernel<<<162, 256, 0, stream>>>(Gf, GAh, GAl);
    prep_packd_kernel<<<6, 256, 0, stream>>>(D, DAh, DAl);
    conv_b_kernel<<<BATCH*49, 256, 0, stream>>>(x, DAh, DAl, b, u0);
    float* uin = u0; float* uo2 = u1;
    for (int it = 0; it < 9; ++it) {       // iterations 2..10 (iter 1 folded)
        int last = (it == 8);
        lca_iter_kernel<<<BATCH*49, 256, 0, stream>>>(b, uin, uo2, GAh, GAl, out, last);
        float* tmp = uin; uin = uo2; uo2 = tmp;
    }
}

// Round 4
// 5055.556 us; speedup vs baseline: 2.2722x; 1.1464x over previous
//
#include <hip/hip_runtime.h>

#define BATCH 64
#define ATOMS 64
#define CIN 3
#define KS 8
#define H 224
#define W 224
#define OH 56
#define OW 56
#define NLAT (BATCH*ATOMS*OH*OW)   // 12,845,056
#define LAM 0.1f
#define ETA 0.1f

typedef __attribute__((ext_vector_type(8)))  __bf16 bf16x8;
typedef __attribute__((ext_vector_type(16))) float  floatx16;

union FragU { uint4 u; bf16x8 v; };

__device__ __forceinline__ float softthr(float u) {
    float p = u - LAM;  p = p > 0.f ? p : 0.f;
    float q = -u - LAM; q = q > 0.f ? q : 0.f;
    return p - q;
}
__device__ __forceinline__ unsigned short f2bf(float f) {   // RNE
    union { float f; unsigned int u; } c; c.f = f;
    unsigned int r = c.u + 0x7fffu + ((c.u >> 16) & 1u);
    return (unsigned short)(r >> 16);
}
__device__ __forceinline__ float bf2f(unsigned short h) {
    union { unsigned int u; float f; } c; c.u = ((unsigned int)h) << 16;
    return c.f;
}

// DT[((c*8+y)*8+x)*64 + m] = D[m,c,y,x]
__global__ void prep_dt_kernel(const float* __restrict__ D,
                               float* __restrict__ DT) {
    int idx = blockIdx.x * 256 + threadIdx.x;
    if (idx < CIN*KS*KS*ATOMS) {
        int m = idx & 63;
        int r = idx >> 6;
        int xk = r & 7, y = (r >> 3) & 7, c = r >> 6;
        DT[idx] = D[((m*CIN + c)*KS + y)*KS + xk];
    }
}

// 9 table-sets (inclusion-exclusion for boundary classes), 9 dpq each.
// tbl: 0=T0(all) 1=-dY1 2=-dY2 3=-dX1 4=-dX2 5=+dC11 6=+dC12 7=+dC21 8=+dC22
// di = 1-dp; second kernel row = y + 4*di. Clips: Y1 removes y in [0,2),
// Y2 removes y in [6,8) (image-boundary rows at i==0 / i==55).
__global__ void prep_gram_kernel(const float* __restrict__ DT,
                                 float* __restrict__ G) {
    int blk = blockIdx.x;              // tbl*9 + dpq
    int tbl = blk / 9, dpq = blk % 9;
    int dp = dpq / 3, dq = dpq % 3;
    int di = 1 - dp, dj = 1 - dq;
    int ylo = (0 > -4*di) ? 0 : -4*di;
    int yhi = (8 < 8-4*di) ? 8 : 8-4*di;
    int xlo = (0 > -4*dj) ? 0 : -4*dj;
    int xhi = (8 < 8-4*dj) ? 8 : 8-4*dj;
    if (tbl==1 || tbl==5 || tbl==6) { if (yhi > 2) yhi = 2; }
    if (tbl==2 || tbl==7 || tbl==8) { if (ylo < 6) ylo = 6; }
    if (tbl==3 || tbl==5 || tbl==7) { if (xhi > 2) xhi = 2; }
    if (tbl==4 || tbl==6 || tbl==8) { if (xlo < 6) xlo = 6; }
    float sign = (tbl >= 1 && tbl <= 4) ? -1.f : 1.f;
    int t = threadIdx.x;
    int m = t & 63;
    int nb = (t >> 6) * 16;
    for (int k = 0; k < 16; ++k) {
        int n = nb + k;
        float s = 0.f;
        for (int c = 0; c < CIN; ++c)
            for (int y = ylo; y < yhi; ++y)
                for (int x = xlo; x < xhi; ++x)
                    s += DT[((c*8+y)*8+x)*64 + m] *
                         DT[((c*8+y+4*di)*8 + (x+4*dj))*64 + n];
        G[blk*4096 + n*64 + m] = sign * s;
    }
}

// Pack G into MFMA A-operand layout, split bf16 hi/lo.
// uint4 index g = (((tbl*9+dpq)*2+mhalf)*4+kstep)*64 + lane; 8 bf16 per lane.
// A[m][k=n]: m = mhalf*32+(lane&31), n = kstep*16+(lane>>5)*8+j.
__global__ void prep_packg_kernel(const float* __restrict__ G,
                                  unsigned short* __restrict__ GAh,
                                  unsigned short* __restrict__ GAl) {
    int g = blockIdx.x * 256 + threadIdx.x;      // 162*256 = 41472 groups
    int lane = g & 63;
    int r = g >> 6;
    int kstep = r & 3; r >>= 2;
    int mhalf = r & 1; int td = r >> 1;          // tbl*9+dpq
    int m = mhalf*32 + (lane & 31);
    int n = kstep*16 + (lane >> 5)*8;
    const float* src = G + td*4096 + n*64 + m;
#pragma unroll
    for (int j = 0; j < 8; ++j) {
        float v = src[j*64];
        unsigned short h = f2bf(v);
        GAh[g*8 + j] = h;
        GAl[g*8 + j] = f2bf(v - bf2f(h));
    }
}

// Pack D into MFMA A-layout for conv_b: K=192, k = c*64+y*8+x.
__global__ void prep_packd_kernel(const float* __restrict__ D,
                                  unsigned short* __restrict__ DAh,
                                  unsigned short* __restrict__ DAl) {
    int g = blockIdx.x * 256 + threadIdx.x;      // 6*256 = 1536 groups
    if (g >= 1536) return;
    int lane = g & 63;
    int r = g >> 6;                              // 0..23
    int kstep = r % 12, mhalf = r / 12;
    int m = mhalf*32 + (lane & 31);
    int k0 = kstep*16 + (lane >> 5)*8;
#pragma unroll
    for (int j = 0; j < 8; ++j) {
        float v = D[m*192 + k0 + j];
        unsigned short h = f2bf(v);
        DAh[g*8 + j] = h;
        DAl[g*8 + j] = f2bf(v - bf2f(h));
    }
}

// b = conv2d(x, D, stride4, pad2) via split-bf16 MFMA; u = 0.1*b folded in.
__global__ __launch_bounds__(256) void conv_b_kernel(
        const float* __restrict__ x,
        const unsigned short* __restrict__ DAh,
        const unsigned short* __restrict__ DAl,
        float* __restrict__ b, float* __restrict__ u) {
    __shared__ __align__(16) unsigned short xth[CIN*36*36];
    __shared__ __align__(16) unsigned short xtl[CIN*36*36];
    __shared__ float ot[64*65];
    int blk = blockIdx.x;
    int img = blk / 49, tile = blk % 49;
    int i0 = (tile / 7) * 8, j0 = (tile % 7) * 8;
    int t = threadIdx.x;
    int r0 = 4*i0 - 2, c0 = 4*j0 - 2;
    for (int f = t; f < CIN*36*36; f += 256) {
        int cc = f / 1296, rem = f % 1296;
        int rr = rem / 36, qq = rem % 36;
        int Y = r0 + rr, X = c0 + qq;
        float v = 0.f;
        if (Y >= 0 && Y < H && X >= 0 && X < W)
            v = x[((img*CIN + cc)*H + Y)*W + X];
        unsigned short h = f2bf(v);
        xth[f] = h;
        xtl[f] = f2bf(v - bf2f(h));
    }
    __syncthreads();
    int lane = t & 63, wave = t >> 6;
    int mhalf = wave & 1, poshalf = wave >> 1;
    int pos = poshalf*32 + (lane & 31), pi = pos >> 3, pj = pos & 7;
    int khalf = lane >> 5;
    floatx16 acc;
#pragma unroll
    for (int i = 0; i < 16; ++i) acc[i] = 0.f;
    const uint4* Ah4 = (const uint4*)DAh;
    const uint4* Al4 = (const uint4*)DAl;
#pragma unroll 3
    for (int kstep = 0; kstep < 12; ++kstep) {
        int k0 = kstep*16 + khalf*8;
        int cc = k0 >> 6, yy = (k0 >> 3) & 7;
        int boff = cc*1296 + (4*pi + yy)*36 + 4*pj;   // %4==0 -> 8B aligned
        FragU ah, al, bh, bl;
        ah.u = Ah4[(mhalf*12 + kstep)*64 + lane];
        al.u = Al4[(mhalf*12 + kstep)*64 + lane];
        const uint2* ph = (const uint2*)(xth + boff);
        uint2 h0 = ph[0], h1 = ph[1];
        bh.u = make_uint4(h0.x, h0.y, h1.x, h1.y);
        const uint2* pl = (const uint2*)(xtl + boff);
        uint2 l0 = pl[0], l1 = pl[1];
        bl.u = make_uint4(l0.x, l0.y, l1.x, l1.y);
        acc = __builtin_amdgcn_mfma_f32_32x32x16_bf16(ah.v, bh.v, acc, 0, 0, 0);
        acc = __builtin_amdgcn_mfma_f32_32x32x16_bf16(ah.v, bl.v, acc, 0, 0, 0);
        acc = __builtin_amdgcn_mfma_f32_32x32x16_bf16(al.v, bh.v, acc, 0, 0, 0);
    }
#pragma unroll
    for (int r16 = 0; r16 < 16; ++r16) {   // C layout: col=lane&31,
        int row = (r16 & 3) + 8*(r16 >> 2) + 4*khalf;  // row=(reg&3)+8*(reg>>2)+4*(lane>>5)
        ot[(mhalf*32 + row)*65 + pos] = acc[r16];
    }
    __syncthreads();
#pragma unroll
    for (int e = 0; e < 16; ++e) {
        int flat = e*256 + t;
        int mm = flat >> 6, pp = flat & 63;
        int gi = ((img*ATOMS + mm)*OH + i0 + (pp >> 3))*OW + j0 + (pp & 7);
        float v = ot[mm*65 + pp];
        b[gi] = v;
        u[gi] = ETA * v;
    }
}

// One LCA step. gram = sum over active table-sets of (G_tbl * a) as
// 32x32x16 bf16 MFMA GEMMs (split hi/lo, 3 cross terms), per-lane column
// masks implementing boundary classes. at2 tile is XOR-swizzled: 16B group
// (rc, kg) lives at slot kg ^ (rc&7)  -> B-fragment ds_read_b128 hits the
// conflict-free floor instead of 32-way on 4 banks.
__global__ __launch_bounds__(256, 4) void lca_iter_kernel(
        const float* __restrict__ b, const float* __restrict__ uin,
        float* __restrict__ uout,
        const unsigned short* __restrict__ GAh,
        const unsigned short* __restrict__ GAl,
        float* __restrict__ out, int last) {
    __shared__ __align__(16) unsigned short smem[12800];  // 25.6 KB total
    unsigned short* at2h = smem;          // [rc][swizzled n], 12.8 KB
    unsigned short* at2l = smem + 6400;   // 12.8 KB
    int blk = blockIdx.x;
    int img = blk / 49, tile = blk % 49;
    int ti = tile / 7, tj = tile % 7;
    int i0 = ti*8, j0 = tj*8;
    int t = threadIdx.x;
    // Phase 1 (fused): one halo row (10 a-values) per thread-iteration.
    // 4 aligned float4 loads cover j0-4..j0+11 (line-aligned, 64B).
    const float* ubase = uin + (size_t)img*ATOMS*OH*OW;
    for (int row = t; row < 640; row += 256) {
        int n = row / 10;
        int p = row - 10*n;
        int gi = i0 - 1 + p;
        bool rowok = (gi >= 0 && gi < OH);
        float buf[16];
        if (rowok) {
            const float4* s4 = (const float4*)(ubase + ((n*OH + gi)*OW + j0 - 4));
            float4 a0 = s4[0], a1 = s4[1], a2 = s4[2], a3 = s4[3];
            buf[0]=a0.x; buf[1]=a0.y; buf[2]=a0.z; buf[3]=a0.w;
            buf[4]=a1.x; buf[5]=a1.y; buf[6]=a1.z; buf[7]=a1.w;
            buf[8]=a2.x; buf[9]=a2.y; buf[10]=a2.z; buf[11]=a2.w;
            buf[12]=a3.x; buf[13]=a3.y; buf[14]=a3.z; buf[15]=a3.w;
        }
        int rc0 = p*10;
        int kg = n >> 3, nl = n & 7;
#pragma unroll
        for (int q = 0; q < 10; ++q) {
            int gj = j0 - 1 + q;
            float v = (rowok && gj >= 0 && gj < OW) ? buf[q+3] : 0.f;
            float a = softthr(v);
            unsigned short h = f2bf(a);
            unsigned short lo = f2bf(a - bf2f(h));
            int rc = rc0 + q;
            int idx = rc*64 + ((kg ^ (rc & 7)) << 3) + nl;
            at2h[idx] = h;
            at2l[idx] = lo;
        }
    }
    __syncthreads();
    int lane = t & 63, wave = t >> 6;
    int mhalf = wave & 1, poshalf = wave >> 1;
    int pos = poshalf*32 + (lane & 31), pi = pos >> 3, pj = pos & 7;
    int khalf = lane >> 5;
    floatx16 acc;
#pragma unroll
    for (int i = 0; i < 16; ++i) acc[i] = 0.f;
    const uint4* Gh4 = (const uint4*)GAh;
    const uint4* Gl4 = (const uint4*)GAl;
    const uint4* B4h = (const uint4*)at2h;
    const uint4* B4l = (const uint4*)at2l;
    int tbls[4]; bool msks[4]; int nt = 0;
    tbls[0] = 0; msks[0] = true; nt = 1;
    if (ti == 0) { tbls[nt] = 1; msks[nt] = (pi == 0); ++nt; }
    if (ti == 6) { tbls[nt] = 2; msks[nt] = (pi == 7); ++nt; }
    if (tj == 0) { tbls[nt] = 3; msks[nt] = (pj == 0); ++nt; }
    if (tj == 6) { tbls[nt] = 4; msks[nt] = (pj == 7); ++nt; }
    if (ti == 0 && tj == 0) { tbls[nt] = 5; msks[nt] = (pi==0 && pj==0); ++nt; }
    if (ti == 0 && tj == 6) { tbls[nt] = 6; msks[nt] = (pi==0 && pj==7); ++nt; }
    if (ti == 6 && tj == 0) { tbls[nt] = 7; msks[nt] = (pi==7 && pj==0); ++nt; }
    if (ti == 6 && tj == 6) { tbls[nt] = 8; msks[nt] = (pi==7 && pj==7); ++nt; }
    for (int it = 0; it < nt; ++it) {            // block-uniform term loop
        int tb = tbls[it]; bool mk = msks[it];
        for (int dpq = 0; dpq < 9; ++dpq) {
            int dp = dpq / 3, dq = dpq - 3*dp;
            int rc = (pi + dp)*10 + (pj + dq);
            int rbase = rc*8, rx = rc & 7;
            int abase = (((tb*9 + dpq)*2 + mhalf)*4)*64 + lane;
#pragma unroll
            for (int kstep = 0; kstep < 4; ++kstep) {
                FragU ah, al, bh, bl;
                ah.u = Gh4[abase + kstep*64];
                al.u = Gl4[abase + kstep*64];
                int slot = (kstep*2 + khalf) ^ rx;
                bh.u = B4h[rbase + slot];
                bl.u = B4l[rbase + slot];
                if (!mk) { bh.u = make_uint4(0,0,0,0); bl.u = make_uint4(0,0,0,0); }
                acc = __builtin_amdgcn_mfma_f32_32x32x16_bf16(ah.v, bh.v, acc, 0,0,0);
                acc = __builtin_amdgcn_mfma_f32_32x32x16_bf16(ah.v, bl.v, acc, 0,0,0);
                acc = __builtin_amdgcn_mfma_f32_32x32x16_bf16(al.v, bh.v, acc, 0,0,0);
            }
        }
    }
    __syncthreads();                   // at2 dead; reuse smem as fp32 ot
    float* ot = (float*)smem;          // 64*65*4 = 16.6 KB <= 25.6 KB
#pragma unroll
    for (int r16 = 0; r16 < 16; ++r16) {
        int row = (r16 & 3) + 8*(r16 >> 2) + 4*khalf;
        ot[(mhalf*32 + row)*65 + pos] = acc[r16];
    }
    __syncthreads();
#pragma unroll
    for (int e = 0; e < 16; ++e) {     // j-coalesced fp32 update
        int flat = e*256 + t;
        int mm = flat >> 6, pp = flat & 63;
        int gi = ((img*ATOMS + mm)*OH + i0 + (pp >> 3))*OW + j0 + (pp & 7);
        float uo = uin[gi];
        float gram = ot[mm*65 + pp];
        float un = uo + ETA * (b[gi] - uo - gram + softthr(uo));
        if (last) out[gi] = softthr(un);
        else      uout[gi] = un;
    }
}

extern "C" void kernel_launch(void* const* d_in, const int* in_sizes, int n_in,
                              void* d_out, int out_size, void* d_ws, size_t ws_size,
                              hipStream_t stream) {
    const float* x = (const float*)d_in[0];
    const float* D = (const float*)d_in[1];
    float* out = (float*)d_out;
    float* ws = (float*)d_ws;
    float* b  = ws;                        // NLAT f32
    float* u0 = b  + NLAT;                 // NLAT f32
    float* u1 = u0 + NLAT;                 // NLAT f32
    float* DT = u1 + NLAT;                 // 12288 f32
    float* Gf = DT + 12288;                // 81*4096 = 331776 f32
    unsigned short* GAh = (unsigned short*)(Gf + 331776);   // 331776 bf16
    unsigned short* GAl = GAh + 331776;
    unsigned short* DAh = GAl + 331776;    // 12288 bf16
    unsigned short* DAl = DAh + 12288;
    prep_dt_kernel<<<48, 256, 0, stream>>>(D, DT);
    prep_gram_kernel<<<81, 256, 0, stream>>>(DT, Gf);
    prep_packg_kernel<<<162, 256, 0, stream>>>(Gf, GAh, GAl);
    prep_packd_kernel<<<6, 256, 0, stream>>>(D, DAh, DAl);
    conv_b_kernel<<<BATCH*49, 256, 0, stream>>>(x, DAh, DAl, b, u0);
    float* uin = u0; float* uo2 = u1;
    for (int it = 0; it < 9; ++it) {       // iterations 2..10 (iter 1 folded)
        int last = (it == 8);
        lca_iter_kernel<<<BATCH*49, 256, 0, stream>>>(b, uin, uo2, GAh, GAl, out, last);
        float* tmp = uin; uin = uo2; uo2 = tmp;
    }
}

// Round 5
// 2229.507 us; speedup vs baseline: 5.1523x; 2.2676x over previous
//
#include <hip/hip_runtime.h>

#define BATCH 64
#define ATOMS 64
#define CIN 3
#define KS 8
#define H 224
#define W 224
#define OH 56
#define OW 56
#define NLAT (BATCH*ATOMS*OH*OW)   // 12,845,056
#define IMGSZ (OH*OW*ATOMS)        // 200,704 elems per image (channel-last)
#define LAM 0.1f
#define ETA 0.1f

typedef __attribute__((ext_vector_type(8)))  __bf16 bf16x8;
typedef __attribute__((ext_vector_type(16))) float  floatx16;

union FragU { uint4 u; bf16x8 v; };

__device__ __forceinline__ float softthr(float u) {
    float p = u - LAM;  p = p > 0.f ? p : 0.f;
    float q = -u - LAM; q = q > 0.f ? q : 0.f;
    return p - q;
}
__device__ __forceinline__ unsigned short f2bf(float f) {   // RNE
    union { float f; unsigned int u; } c; c.f = f;
    unsigned int r = c.u + 0x7fffu + ((c.u >> 16) & 1u);
    return (unsigned short)(r >> 16);
}
__device__ __forceinline__ float bf2f(unsigned short h) {
    union { unsigned int u; float f; } c; c.u = ((unsigned int)h) << 16;
    return c.f;
}

// DT[((c*8+y)*8+x)*64 + m] = D[m,c,y,x]
__global__ void prep_dt_kernel(const float* __restrict__ D,
                               float* __restrict__ DT) {
    int idx = blockIdx.x * 256 + threadIdx.x;
    if (idx < CIN*KS*KS*ATOMS) {
        int m = idx & 63;
        int r = idx >> 6;
        int xk = r & 7, y = (r >> 3) & 7, c = r >> 6;
        DT[idx] = D[((m*CIN + c)*KS + y)*KS + xk];
    }
}

// 9 table-sets (inclusion-exclusion for boundary classes), 9 dpq each.
// tbl: 0=T0(all) 1=-dY1 2=-dY2 3=-dX1 4=-dX2 5=+dC11 6=+dC12 7=+dC21 8=+dC22
__global__ void prep_gram_kernel(const float* __restrict__ DT,
                                 float* __restrict__ G) {
    int blk = blockIdx.x;              // tbl*9 + dpq
    int tbl = blk / 9, dpq = blk % 9;
    int dp = dpq / 3, dq = dpq % 3;
    int di = 1 - dp, dj = 1 - dq;
    int ylo = (0 > -4*di) ? 0 : -4*di;
    int yhi = (8 < 8-4*di) ? 8 : 8-4*di;
    int xlo = (0 > -4*dj) ? 0 : -4*dj;
    int xhi = (8 < 8-4*dj) ? 8 : 8-4*dj;
    if (tbl==1 || tbl==5 || tbl==6) { if (yhi > 2) yhi = 2; }
    if (tbl==2 || tbl==7 || tbl==8) { if (ylo < 6) ylo = 6; }
    if (tbl==3 || tbl==5 || tbl==7) { if (xhi > 2) xhi = 2; }
    if (tbl==4 || tbl==6 || tbl==8) { if (xlo < 6) xlo = 6; }
    float sign = (tbl >= 1 && tbl <= 4) ? -1.f : 1.f;
    int t = threadIdx.x;
    int m = t & 63;
    int nb = (t >> 6) * 16;
    for (int k = 0; k < 16; ++k) {
        int n = nb + k;
        float s = 0.f;
        for (int c = 0; c < CIN; ++c)
            for (int y = ylo; y < yhi; ++y)
                for (int x = xlo; x < xhi; ++x)
                    s += DT[((c*8+y)*8+x)*64 + m] *
                         DT[((c*8+y+4*di)*8 + (x+4*dj))*64 + n];
        G[blk*4096 + n*64 + m] = sign * s;
    }
}

// Pack G into MFMA A-operand layout, split bf16 hi/lo.
__global__ void prep_packg_kernel(const float* __restrict__ G,
                                  unsigned short* __restrict__ GAh,
                                  unsigned short* __restrict__ GAl) {
    int g = blockIdx.x * 256 + threadIdx.x;      // 162*256 = 41472 groups
    int lane = g & 63;
    int r = g >> 6;
    int kstep = r & 3; r >>= 2;
    int mhalf = r & 1; int td = r >> 1;          // tbl*9+dpq
    int m = mhalf*32 + (lane & 31);
    int n = kstep*16 + (lane >> 5)*8;
    const float* src = G + td*4096 + n*64 + m;
#pragma unroll
    for (int j = 0; j < 8; ++j) {
        float v = src[j*64];
        unsigned short h = f2bf(v);
        GAh[g*8 + j] = h;
        GAl[g*8 + j] = f2bf(v - bf2f(h));
    }
}

// Pack D into MFMA A-layout for conv_b: K=192, k = c*64+y*8+x.
__global__ void prep_packd_kernel(const float* __restrict__ D,
                                  unsigned short* __restrict__ DAh,
                                  unsigned short* __restrict__ DAl) {
    int g = blockIdx.x * 256 + threadIdx.x;
    if (g >= 1536) return;
    int lane = g & 63;
    int r = g >> 6;
    int kstep = r % 12, mhalf = r / 12;
    int m = mhalf*32 + (lane & 31);
    int k0 = kstep*16 + (lane >> 5)*8;
#pragma unroll
    for (int j = 0; j < 8; ++j) {
        float v = D[m*192 + k0 + j];
        unsigned short h = f2bf(v);
        DAh[g*8 + j] = h;
        DAl[g*8 + j] = f2bf(v - bf2f(h));
    }
}

// b = conv2d(x, D, stride4, pad2); u = 0.1*b. Output CHANNEL-LAST [i][j][n].
__global__ __launch_bounds__(256) void conv_b_kernel(
        const float* __restrict__ x,
        const unsigned short* __restrict__ DAh,
        const unsigned short* __restrict__ DAl,
        float* __restrict__ b, float* __restrict__ u) {
    __shared__ __align__(16) unsigned short xth[CIN*36*36];
    __shared__ __align__(16) unsigned short xtl[CIN*36*36];
    __shared__ float ot[64*65];
    int blk = blockIdx.x;
    int img = blk / 49, tile = blk % 49;
    int i0 = (tile / 7) * 8, j0 = (tile % 7) * 8;
    int t = threadIdx.x;
    int r0 = 4*i0 - 2, c0 = 4*j0 - 2;
    for (int f = t; f < CIN*36*36; f += 256) {
        int cc = f / 1296, rem = f % 1296;
        int rr = rem / 36, qq = rem % 36;
        int Y = r0 + rr, X = c0 + qq;
        float v = 0.f;
        if (Y >= 0 && Y < H && X >= 0 && X < W)
            v = x[((img*CIN + cc)*H + Y)*W + X];
        unsigned short h = f2bf(v);
        xth[f] = h;
        xtl[f] = f2bf(v - bf2f(h));
    }
    __syncthreads();
    int lane = t & 63, wave = t >> 6;
    int mhalf = wave & 1, poshalf = wave >> 1;
    int pos = poshalf*32 + (lane & 31), pi = pos >> 3, pj = pos & 7;
    int khalf = lane >> 5;
    floatx16 acc;
#pragma unroll
    for (int i = 0; i < 16; ++i) acc[i] = 0.f;
    const uint4* Ah4 = (const uint4*)DAh;
    const uint4* Al4 = (const uint4*)DAl;
#pragma unroll 3
    for (int kstep = 0; kstep < 12; ++kstep) {
        int k0 = kstep*16 + khalf*8;
        int cc = k0 >> 6, yy = (k0 >> 3) & 7;
        int boff = cc*1296 + (4*pi + yy)*36 + 4*pj;
        FragU ah, al, bh, bl;
        ah.u = Ah4[(mhalf*12 + kstep)*64 + lane];
        al.u = Al4[(mhalf*12 + kstep)*64 + lane];
        const uint2* ph = (const uint2*)(xth + boff);
        uint2 h0 = ph[0], h1 = ph[1];
        bh.u = make_uint4(h0.x, h0.y, h1.x, h1.y);
        const uint2* pl = (const uint2*)(xtl + boff);
        uint2 l0 = pl[0], l1 = pl[1];
        bl.u = make_uint4(l0.x, l0.y, l1.x, l1.y);
        acc = __builtin_amdgcn_mfma_f32_32x32x16_bf16(ah.v, bh.v, acc, 0, 0, 0);
        acc = __builtin_amdgcn_mfma_f32_32x32x16_bf16(ah.v, bl.v, acc, 0, 0, 0);
        acc = __builtin_amdgcn_mfma_f32_32x32x16_bf16(al.v, bh.v, acc, 0, 0, 0);
    }
#pragma unroll
    for (int r16 = 0; r16 < 16; ++r16) {
        int row = (r16 & 3) + 8*(r16 >> 2) + 4*khalf;
        ot[(mhalf*32 + row)*65 + pos] = acc[r16];
    }
    __syncthreads();
    // channel-last epilogue: lane = channel -> 256B contiguous stores
    int m = t & 63;
    float* bp = b + (size_t)img*IMGSZ;
    float* up = u + (size_t)img*IMGSZ;
#pragma unroll
    for (int e = 0; e < 16; ++e) {
        int pp = e*4 + (t >> 6);
        int gi = ((i0 + (pp >> 3))*OW + j0 + (pp & 7))*64 + m;
        float v = ot[m*65 + pp];
        bp[gi] = v;
        up[gi] = ETA * v;
    }
}

// One LCA step on a 2-row x 56-col band (channel-last state).
// gram = sum over table-sets of (G_tbl * a) as 32x32x16 bf16 MFMA (split
// hi/lo, 3 terms; masked correction terms use 1 term). B-tile [rc][n] in
// LDS is XOR-swizzled (16B group kg at slot kg^(rc&7)).
__global__ __launch_bounds__(256, 2) void lca_iter_kernel(
        const float* __restrict__ b, const float* __restrict__ uin,
        float* __restrict__ uout,
        const unsigned short* __restrict__ GAh,
        const unsigned short* __restrict__ GAl,
        float* __restrict__ out, int last) {
    __shared__ __align__(16) unsigned short smem[2*232*64];  // 59.4 KB
    unsigned short* at2h = smem;
    unsigned short* at2l = smem + 232*64;
    int blk = blockIdx.x;
    int img = blk / 28, bandi = blk % 28;
    int i0 = bandi*2;
    int t = threadIdx.x;
    const float* ub = uin + (size_t)img*IMGSZ;
    // Phase 1: halo band (4 rows x 58 cols x 64 n) -> soft -> split -> LDS.
    // Full-line 16B loads, already in [rc][n] B-operand order.
    for (int idx = t; idx < 232*16; idx += 256) {
        int chunk = idx >> 4, f4 = idx & 15;
        int p = chunk / 58, q = chunk - 58*p;
        int gi = i0 - 1 + p, gj = q - 1;
        int n0 = f4 << 2;
        float4 v = make_float4(0.f, 0.f, 0.f, 0.f);
        if (gi >= 0 && gi < OH && gj >= 0 && gj < OW)
            v = *(const float4*)(ub + ((gi*OW + gj)*64 + n0));
        float a0 = softthr(v.x), a1 = softthr(v.y),
              a2 = softthr(v.z), a3 = softthr(v.w);
        unsigned short h0 = f2bf(a0), h1 = f2bf(a1),
                       h2 = f2bf(a2), h3 = f2bf(a3);
        ushort4 hv = make_ushort4(h0, h1, h2, h3);
        ushort4 lv = make_ushort4(f2bf(a0 - bf2f(h0)), f2bf(a1 - bf2f(h1)),
                                  f2bf(a2 - bf2f(h2)), f2bf(a3 - bf2f(h3)));
        int kg = n0 >> 3;
        int base = chunk*64 + ((kg ^ (chunk & 7)) << 3) + (n0 & 7);
        *(ushort4*)(at2h + base) = hv;
        *(ushort4*)(at2l + base) = lv;
    }
    __syncthreads();
    int lane = t & 63, wave = t >> 6;
    int mhalf = wave & 1, cgrp = wave >> 1;      // cgrp: pj 0..31 / 32..63
    int khalf = lane >> 5, cl = lane & 31;
    int pj = cgrp*32 + cl;
    int pjx = (pj < 56) ? pj : 0;                // clamp invalid columns
    floatx16 acc0, acc1;
#pragma unroll
    for (int i = 0; i < 16; ++i) { acc0[i] = 0.f; acc1[i] = 0.f; }
    const uint4* Gh4 = (const uint4*)GAh;
    const uint4* Gl4 = (const uint4*)GAl;
    const uint4* B4h = (const uint4*)at2h;
    const uint4* B4l = (const uint4*)at2l;
    // term list: tb, cti-mask (1=pi0,2=pi1,3=both), lane-select (-1=all)
    int tbs[4], cms[4], lss[4]; int nt = 0;
    tbs[0] = 0; cms[0] = 3; lss[0] = -1; nt = 1;
    tbs[1] = (cgrp == 0) ? 3 : 4; cms[1] = 3; lss[1] = (cgrp == 0) ? 0 : 23; nt = 2;
    if (bandi == 0)  { tbs[nt] = 1; cms[nt] = 1; lss[nt] = -1; ++nt;
                       tbs[nt] = (cgrp == 0) ? 5 : 6; cms[nt] = 1;
                       lss[nt] = (cgrp == 0) ? 0 : 23; ++nt; }
    if (bandi == 27) { tbs[nt] = 2; cms[nt] = 2; lss[nt] = -1; ++nt;
                       tbs[nt] = (cgrp == 0) ? 7 : 8; cms[nt] = 2;
                       lss[nt] = (cgrp == 0) ? 0 : 23; ++nt; }
    for (int it = 0; it < nt; ++it) {
        int tb = tbs[it], cm = cms[it], ls = lss[it];
        bool full = (ls < 0);
        bool lm = full || (cl == ls);
        for (int dpq = 0; dpq < 9; ++dpq) {
            int dp = dpq / 3, dq = dpq - 3*dp;
            int rc0 = dp*58 + pjx + dq;
            int abase = (((tb*9 + dpq)*2 + mhalf)*4)*64 + lane;
#pragma unroll
            for (int kstep = 0; kstep < 4; ++kstep) {
                FragU ah, al;
                ah.u = Gh4[abase + kstep*64];
                if (full) al.u = Gl4[abase + kstep*64];
                int kg2 = kstep*2 + khalf;
                if (cm & 1) {
                    int rc = rc0;
                    int slot = kg2 ^ (rc & 7);
                    FragU bh, bl;
                    bh.u = B4h[rc*8 + slot];
                    if (!lm) bh.u = make_uint4(0, 0, 0, 0);
                    acc0 = __builtin_amdgcn_mfma_f32_32x32x16_bf16(ah.v, bh.v, acc0, 0,0,0);
                    if (full) {
                        bl.u = B4l[rc*8 + slot];
                        acc0 = __builtin_amdgcn_mfma_f32_32x32x16_bf16(ah.v, bl.v, acc0, 0,0,0);
                        acc0 = __builtin_amdgcn_mfma_f32_32x32x16_bf16(al.v, bh.v, acc0, 0,0,0);
                    }
                }
                if (cm & 2) {
                    int rc = rc0 + 58;
                    int slot = kg2 ^ (rc & 7);
                    FragU bh, bl;
                    bh.u = B4h[rc*8 + slot];
                    if (!lm) bh.u = make_uint4(0, 0, 0, 0);
                    acc1 = __builtin_amdgcn_mfma_f32_32x32x16_bf16(ah.v, bh.v, acc1, 0,0,0);
                    if (full) {
                        bl.u = B4l[rc*8 + slot];
                        acc1 = __builtin_amdgcn_mfma_f32_32x32x16_bf16(ah.v, bl.v, acc1, 0,0,0);
                        acc1 = __builtin_amdgcn_mfma_f32_32x32x16_bf16(al.v, bh.v, acc1, 0,0,0);
                    }
                }
            }
        }
    }
    __syncthreads();                   // at2 dead; overlay fp32 ot[pos][m]
    float* ot = (float*)smem;          // 128*65*4 = 33.3 KB <= 59.4 KB
#pragma unroll
    for (int r16 = 0; r16 < 16; ++r16) {
        int row = (r16 & 3) + 8*(r16 >> 2) + 4*khalf;
        int m = mhalf*32 + row;
        ot[pj*65 + m] = acc0[r16];
        ot[(64 + pj)*65 + m] = acc1[r16];
    }
    __syncthreads();
    const float* bp = b + (size_t)img*IMGSZ;
    float* up = uout + (size_t)img*IMGSZ;
#pragma unroll 4
    for (int pass = 0; pass < 28; ++pass) {     // 2*56*64 elems, lane = n
        int idx = pass*256 + t;
        int n = idx & 63;
        int rest = idx >> 6;                    // 0..111
        int pi = (rest >= 56) ? 1 : 0;
        int j = rest - 56*pi;
        int g = ((i0 + pi)*OW + j)*64 + n;
        float uo = ub[g];
        float gram = ot[(pi*64 + j)*65 + n];
        float un = uo + ETA * (bp[g] - uo - gram + softthr(uo));
        if (last) out[(((size_t)img*ATOMS + n)*OH + (i0 + pi))*OW + j] = softthr(un);
        else      up[g] = un;
    }
}

extern "C" void kernel_launch(void* const* d_in, const int* in_sizes, int n_in,
                              void* d_out, int out_size, void* d_ws, size_t ws_size,
                              hipStream_t stream) {
    const float* x = (const float*)d_in[0];
    const float* D = (const float*)d_in[1];
    float* out = (float*)d_out;
    float* ws = (float*)d_ws;
    float* b  = ws;                        // NLAT f32 (channel-last)
    float* u0 = b  + NLAT;                 // NLAT f32
    float* u1 = u0 + NLAT;                 // NLAT f32
    float* DT = u1 + NLAT;                 // 12288 f32
    float* Gf = DT + 12288;                // 81*4096 f32
    unsigned short* GAh = (unsigned short*)(Gf + 331776);
    unsigned short* GAl = GAh + 331776;
    unsigned short* DAh = GAl + 331776;
    unsigned short* DAl = DAh + 12288;
    prep_dt_kernel<<<48, 256, 0, stream>>>(D, DT);
    prep_gram_kernel<<<81, 256, 0, stream>>>(DT, Gf);
    prep_packg_kernel<<<162, 256, 0, stream>>>(Gf, GAh, GAl);
    prep_packd_kernel<<<6, 256, 0, stream>>>(D, DAh, DAl);
    conv_b_kernel<<<BATCH*49, 256, 0, stream>>>(x, DAh, DAl, b, u0);
    float* uin = u0; float* uo2 = u1;
    for (int it = 0; it < 9; ++it) {       // iterations 2..10 (iter 1 folded)
        int last = (it == 8);
        lca_iter_kernel<<<BATCH*28, 256, 0, stream>>>(b, uin, uo2, GAh, GAl, out, last);
        float* tmp = uin; uin = uo2; uo2 = tmp;
    }
}

// Round 6
// 1843.704 us; speedup vs baseline: 6.2305x; 1.2093x over previous
//
#include <hip/hip_runtime.h>

#define BATCH 64
#define ATOMS 64
#define CIN 3
#define KS 8
#define H 224
#define W 224
#define OH 56
#define OW 56
#define NLAT (BATCH*ATOMS*OH*OW)   // 12,845,056
#define IMGSZ (OH*OW*ATOMS)        // 200,704 elems per image (channel-last)
#define LAM 0.1f
#define ETA 0.1f

typedef __attribute__((ext_vector_type(8)))  __bf16 bf16x8;
typedef __attribute__((ext_vector_type(16))) float  floatx16;

union FragU { uint4 u; bf16x8 v; };

__device__ __forceinline__ float softthr(float u) {
    float p = u - LAM;  p = p > 0.f ? p : 0.f;
    float q = -u - LAM; q = q > 0.f ? q : 0.f;
    return p - q;
}
__device__ __forceinline__ unsigned short f2bf(float f) {   // RNE
    union { float f; unsigned int u; } c; c.f = f;
    unsigned int r = c.u + 0x7fffu + ((c.u >> 16) & 1u);
    return (unsigned short)(r >> 16);
}
__device__ __forceinline__ float bf2f(unsigned short h) {
    union { unsigned int u; float f; } c; c.u = ((unsigned int)h) << 16;
    return c.f;
}

// DT[((c*8+y)*8+x)*64 + m] = D[m,c,y,x]
__global__ void prep_dt_kernel(const float* __restrict__ D,
                               float* __restrict__ DT) {
    int idx = blockIdx.x * 256 + threadIdx.x;
    if (idx < CIN*KS*KS*ATOMS) {
        int m = idx & 63;
        int r = idx >> 6;
        int xk = r & 7, y = (r >> 3) & 7, c = r >> 6;
        DT[idx] = D[((m*CIN + c)*KS + y)*KS + xk];
    }
}

// 9 table-sets (inclusion-exclusion for boundary classes), 9 dpq each.
// tbl: 0=T0(all) 1=-dY1 2=-dY2 3=-dX1 4=-dX2 5=+dC11 6=+dC12 7=+dC21 8=+dC22
// Parallelized: 1296 blocks (81 td x 16 n-chunks), 1 entry/thread.
__global__ void prep_gram_kernel(const float* __restrict__ DT,
                                 float* __restrict__ G) {
    int blk = blockIdx.x;              // td*16 + nchunk
    int td = blk >> 4;
    int tbl = td / 9, dpq = td % 9;
    int dp = dpq / 3, dq = dpq % 3;
    int di = 1 - dp, dj = 1 - dq;
    int ylo = (0 > -4*di) ? 0 : -4*di;
    int yhi = (8 < 8-4*di) ? 8 : 8-4*di;
    int xlo = (0 > -4*dj) ? 0 : -4*dj;
    int xhi = (8 < 8-4*dj) ? 8 : 8-4*dj;
    if (tbl==1 || tbl==5 || tbl==6) { if (yhi > 2) yhi = 2; }
    if (tbl==2 || tbl==7 || tbl==8) { if (ylo < 6) ylo = 6; }
    if (tbl==3 || tbl==5 || tbl==7) { if (xhi > 2) xhi = 2; }
    if (tbl==4 || tbl==6 || tbl==8) { if (xlo < 6) xlo = 6; }
    float sign = (tbl >= 1 && tbl <= 4) ? -1.f : 1.f;
    int t = threadIdx.x;
    int m = t & 63;
    int n = (blk & 15)*4 + (t >> 6);
    float s = 0.f;
    for (int c = 0; c < CIN; ++c)
        for (int y = ylo; y < yhi; ++y)
            for (int x = xlo; x < xhi; ++x)
                s += DT[((c*8+y)*8+x)*64 + m] *
                     DT[((c*8+y+4*di)*8 + (x+4*dj))*64 + n];
    G[td*4096 + n*64 + m] = sign * s;
}

// Pack G into MFMA A-operand layout, split bf16 hi/lo.
__global__ void prep_packg_kernel(const float* __restrict__ G,
                                  unsigned short* __restrict__ GAh,
                                  unsigned short* __restrict__ GAl) {
    int g = blockIdx.x * 256 + threadIdx.x;      // 162*256 = 41472 groups
    int lane = g & 63;
    int r = g >> 6;
    int kstep = r & 3; r >>= 2;
    int mhalf = r & 1; int td = r >> 1;          // tbl*9+dpq
    int m = mhalf*32 + (lane & 31);
    int n = kstep*16 + (lane >> 5)*8;
    const float* src = G + td*4096 + n*64 + m;
#pragma unroll
    for (int j = 0; j < 8; ++j) {
        float v = src[j*64];
        unsigned short h = f2bf(v);
        GAh[g*8 + j] = h;
        GAl[g*8 + j] = f2bf(v - bf2f(h));
    }
}

// Pack D into MFMA A-layout for conv_b: K=192, k = c*64+y*8+x.
__global__ void prep_packd_kernel(const float* __restrict__ D,
                                  unsigned short* __restrict__ DAh,
                                  unsigned short* __restrict__ DAl) {
    int g = blockIdx.x * 256 + threadIdx.x;
    if (g >= 1536) return;
    int lane = g & 63;
    int r = g >> 6;
    int kstep = r % 12, mhalf = r / 12;
    int m = mhalf*32 + (lane & 31);
    int k0 = kstep*16 + (lane >> 5)*8;
#pragma unroll
    for (int j = 0; j < 8; ++j) {
        float v = D[m*192 + k0 + j];
        unsigned short h = f2bf(v);
        DAh[g*8 + j] = h;
        DAl[g*8 + j] = f2bf(v - bf2f(h));
    }
}

// b = conv2d(x, D, stride4, pad2); u = 0.1*b. Output CHANNEL-LAST [i][j][n].
__global__ __launch_bounds__(256) void conv_b_kernel(
        const float* __restrict__ x,
        const unsigned short* __restrict__ DAh,
        const unsigned short* __restrict__ DAl,
        float* __restrict__ b, float* __restrict__ u) {
    __shared__ __align__(16) unsigned short xth[CIN*36*36];
    __shared__ __align__(16) unsigned short xtl[CIN*36*36];
    __shared__ float ot[64*65];
    int blk = blockIdx.x;
    int img = blk / 49, tile = blk % 49;
    int i0 = (tile / 7) * 8, j0 = (tile % 7) * 8;
    int t = threadIdx.x;
    int r0 = 4*i0 - 2, c0 = 4*j0 - 2;
    for (int f = t; f < CIN*36*36; f += 256) {
        int cc = f / 1296, rem = f % 1296;
        int rr = rem / 36, qq = rem % 36;
        int Y = r0 + rr, X = c0 + qq;
        float v = 0.f;
        if (Y >= 0 && Y < H && X >= 0 && X < W)
            v = x[((img*CIN + cc)*H + Y)*W + X];
        unsigned short h = f2bf(v);
        xth[f] = h;
        xtl[f] = f2bf(v - bf2f(h));
    }
    __syncthreads();
    int lane = t & 63, wave = t >> 6;
    int mhalf = wave & 1, poshalf = wave >> 1;
    int pos = poshalf*32 + (lane & 31), pi = pos >> 3, pj = pos & 7;
    int khalf = lane >> 5;
    floatx16 acc;
#pragma unroll
    for (int i = 0; i < 16; ++i) acc[i] = 0.f;
    const uint4* Ah4 = (const uint4*)DAh;
    const uint4* Al4 = (const uint4*)DAl;
#pragma unroll 3
    for (int kstep = 0; kstep < 12; ++kstep) {
        int k0 = kstep*16 + khalf*8;
        int cc = k0 >> 6, yy = (k0 >> 3) & 7;
        int boff = cc*1296 + (4*pi + yy)*36 + 4*pj;
        FragU ah, al, bh, bl;
        ah.u = Ah4[(mhalf*12 + kstep)*64 + lane];
        al.u = Al4[(mhalf*12 + kstep)*64 + lane];
        const uint2* ph = (const uint2*)(xth + boff);
        uint2 h0 = ph[0], h1 = ph[1];
        bh.u = make_uint4(h0.x, h0.y, h1.x, h1.y);
        const uint2* pl = (const uint2*)(xtl + boff);
        uint2 l0 = pl[0], l1 = pl[1];
        bl.u = make_uint4(l0.x, l0.y, l1.x, l1.y);
        acc = __builtin_amdgcn_mfma_f32_32x32x16_bf16(ah.v, bh.v, acc, 0, 0, 0);
        acc = __builtin_amdgcn_mfma_f32_32x32x16_bf16(ah.v, bl.v, acc, 0, 0, 0);
        acc = __builtin_amdgcn_mfma_f32_32x32x16_bf16(al.v, bh.v, acc, 0, 0, 0);
    }
#pragma unroll
    for (int r16 = 0; r16 < 16; ++r16) {
        int row = (r16 & 3) + 8*(r16 >> 2) + 4*khalf;
        ot[(mhalf*32 + row)*65 + pos] = acc[r16];
    }
    __syncthreads();
    // channel-last epilogue: lane = channel -> 256B contiguous stores
    int m = t & 63;
    float* bp = b + (size_t)img*IMGSZ;
    float* up = u + (size_t)img*IMGSZ;
#pragma unroll
    for (int e = 0; e < 16; ++e) {
        int pp = e*4 + (t >> 6);
        int gi = ((i0 + (pp >> 3))*OW + j0 + (pp & 7))*64 + m;
        float v = ot[m*65 + pp];
        bp[gi] = v;
        up[gi] = ETA * v;
    }
}

// One LCA step on a 2-row x 56-col band (channel-last state).
// Main loop restructured: B-fragments (bh[4], bl[4] for rows p=0..3 of one
// (dq,kstep) column group) hoisted to VGPRs once, then ALL table-terms
// (T0 3-term split, X-masked, Y/corner on edge bands) consume them from
// registers. LDS b128 reads: 216 -> 96 per wave.
__global__ __launch_bounds__(256, 2) void lca_iter_kernel(
        const float* __restrict__ b, const float* __restrict__ uin,
        float* __restrict__ uout,
        const unsigned short* __restrict__ GAh,
        const unsigned short* __restrict__ GAl,
        float* __restrict__ out, int last) {
    __shared__ __align__(16) unsigned short smem[2*232*64];  // 59.4 KB
    unsigned short* at2h = smem;
    unsigned short* at2l = smem + 232*64;
    int blk = blockIdx.x;
    int img = blk / 28, bandi = blk % 28;
    int i0 = bandi*2;
    int t = threadIdx.x;
    const float* ub = uin + (size_t)img*IMGSZ;
    // Phase 1: halo band (4 rows x 58 cols x 64 n) -> soft -> split -> LDS.
    for (int idx = t; idx < 232*16; idx += 256) {
        int chunk = idx >> 4, f4 = idx & 15;
        int p = chunk / 58, q = chunk - 58*p;
        int gi = i0 - 1 + p, gj = q - 1;
        int n0 = f4 << 2;
        float4 v = make_float4(0.f, 0.f, 0.f, 0.f);
        if (gi >= 0 && gi < OH && gj >= 0 && gj < OW)
            v = *(const float4*)(ub + ((gi*OW + gj)*64 + n0));
        float a0 = softthr(v.x), a1 = softthr(v.y),
              a2 = softthr(v.z), a3 = softthr(v.w);
        unsigned short h0 = f2bf(a0), h1 = f2bf(a1),
                       h2 = f2bf(a2), h3 = f2bf(a3);
        ushort4 hv = make_ushort4(h0, h1, h2, h3);
        ushort4 lv = make_ushort4(f2bf(a0 - bf2f(h0)), f2bf(a1 - bf2f(h1)),
                                  f2bf(a2 - bf2f(h2)), f2bf(a3 - bf2f(h3)));
        int kg = n0 >> 3;
        int base = chunk*64 + ((kg ^ (chunk & 7)) << 3) + (n0 & 7);
        *(ushort4*)(at2h + base) = hv;
        *(ushort4*)(at2l + base) = lv;
    }
    __syncthreads();
    int lane = t & 63, wave = t >> 6;
    int mhalf = wave & 1, cgrp = wave >> 1;      // cgrp: pj 0..31 / 32..63
    int khalf = lane >> 5, cl = lane & 31;
    int pj = cgrp*32 + cl;
    int pjx = (pj < 56) ? pj : 0;                // clamp invalid columns
    floatx16 acc0, acc1;
#pragma unroll
    for (int i = 0; i < 16; ++i) { acc0[i] = 0.f; acc1[i] = 0.f; }
    const uint4* Gh4 = (const uint4*)GAh;
    const uint4* Gl4 = (const uint4*)GAl;
    const uint4* B4h = (const uint4*)at2h;
    const uint4* B4l = (const uint4*)at2l;
    int tbx = (cgrp == 0) ? 3 : 4;               // X boundary table
    unsigned msel = (cl == ((cgrp == 0) ? 0 : 23)) ? 0xFFFFFFFFu : 0u;
    int ymask = 0, tby = 0, tbc = 0;             // Y/corner (edge bands)
    if (bandi == 0)  { ymask = 1; tby = 1; tbc = (cgrp == 0) ? 5 : 6; }
    if (bandi == 27) { ymask = 2; tby = 2; tbc = (cgrp == 0) ? 7 : 8; }
    for (int dq = 0; dq < 3; ++dq) {
        for (int kstep = 0; kstep < 4; ++kstep) {
            int kg2 = kstep*2 + khalf;
            FragU bh[4], bl[4];
#pragma unroll
            for (int p = 0; p < 4; ++p) {
                int rc = p*58 + pjx + dq;
                int slot = kg2 ^ (rc & 7);
                bh[p].u = B4h[rc*8 + slot];
                bl[p].u = B4l[rc*8 + slot];
            }
#pragma unroll
            for (int dp = 0; dp < 3; ++dp) {
                int dpq = 3*dp + dq;
                FragU ah, al, ax, bm0, bm1;
                ah.u = Gh4[((dpq*2 + mhalf)*4 + kstep)*64 + lane];
                al.u = Gl4[((dpq*2 + mhalf)*4 + kstep)*64 + lane];
                ax.u = Gh4[(((tbx*9 + dpq)*2 + mhalf)*4 + kstep)*64 + lane];
                bm0.u = make_uint4(bh[dp].u.x & msel, bh[dp].u.y & msel,
                                   bh[dp].u.z & msel, bh[dp].u.w & msel);
                bm1.u = make_uint4(bh[dp+1].u.x & msel, bh[dp+1].u.y & msel,
                                   bh[dp+1].u.z & msel, bh[dp+1].u.w & msel);
                acc0 = __builtin_amdgcn_mfma_f32_32x32x16_bf16(ah.v, bh[dp].v, acc0, 0,0,0);
                acc0 = __builtin_amdgcn_mfma_f32_32x32x16_bf16(ah.v, bl[dp].v, acc0, 0,0,0);
                acc0 = __builtin_amdgcn_mfma_f32_32x32x16_bf16(al.v, bh[dp].v, acc0, 0,0,0);
                acc0 = __builtin_amdgcn_mfma_f32_32x32x16_bf16(ax.v, bm0.v, acc0, 0,0,0);
                acc1 = __builtin_amdgcn_mfma_f32_32x32x16_bf16(ah.v, bh[dp+1].v, acc1, 0,0,0);
                acc1 = __builtin_amdgcn_mfma_f32_32x32x16_bf16(ah.v, bl[dp+1].v, acc1, 0,0,0);
                acc1 = __builtin_amdgcn_mfma_f32_32x32x16_bf16(al.v, bh[dp+1].v, acc1, 0,0,0);
                acc1 = __builtin_amdgcn_mfma_f32_32x32x16_bf16(ax.v, bm1.v, acc1, 0,0,0);
                if (ymask == 1) {
                    FragU ayh, ayl, ac;
                    ayh.u = Gh4[(((tby*9 + dpq)*2 + mhalf)*4 + kstep)*64 + lane];
                    ayl.u = Gl4[(((tby*9 + dpq)*2 + mhalf)*4 + kstep)*64 + lane];
                    ac.u  = Gh4[(((tbc*9 + dpq)*2 + mhalf)*4 + kstep)*64 + lane];
                    acc0 = __builtin_amdgcn_mfma_f32_32x32x16_bf16(ayh.v, bh[dp].v, acc0, 0,0,0);
                    acc0 = __builtin_amdgcn_mfma_f32_32x32x16_bf16(ayh.v, bl[dp].v, acc0, 0,0,0);
                    acc0 = __builtin_amdgcn_mfma_f32_32x32x16_bf16(ayl.v, bh[dp].v, acc0, 0,0,0);
                    acc0 = __builtin_amdgcn_mfma_f32_32x32x16_bf16(ac.v, bm0.v, acc0, 0,0,0);
                } else if (ymask == 2) {
                    FragU ayh, ayl, ac;
                    ayh.u = Gh4[(((tby*9 + dpq)*2 + mhalf)*4 + kstep)*64 + lane];
                    ayl.u = Gl4[(((tby*9 + dpq)*2 + mhalf)*4 + kstep)*64 + lane];
                    ac.u  = Gh4[(((tbc*9 + dpq)*2 + mhalf)*4 + kstep)*64 + lane];
                    acc1 = __builtin_amdgcn_mfma_f32_32x32x16_bf16(ayh.v, bh[dp+1].v, acc1, 0,0,0);
                    acc1 = __builtin_amdgcn_mfma_f32_32x32x16_bf16(ayh.v, bl[dp+1].v, acc1, 0,0,0);
                    acc1 = __builtin_amdgcn_mfma_f32_32x32x16_bf16(ayl.v, bh[dp+1].v, acc1, 0,0,0);
                    acc1 = __builtin_amdgcn_mfma_f32_32x32x16_bf16(ac.v, bm1.v, acc1, 0,0,0);
                }
            }
        }
    }
    __syncthreads();                   // at2 dead; overlay fp32 ot[pos][m]
    float* ot = (float*)smem;          // 128*65*4 = 33.3 KB <= 59.4 KB
#pragma unroll
    for (int r16 = 0; r16 < 16; ++r16) {
        int row = (r16 & 3) + 8*(r16 >> 2) + 4*khalf;
        int m = mhalf*32 + row;
        ot[pj*65 + m] = acc0[r16];
        ot[(64 + pj)*65 + m] = acc1[r16];
    }
    __syncthreads();
    const float* bp = b + (size_t)img*IMGSZ;
    float* up = uout + (size_t)img*IMGSZ;
#pragma unroll 4
    for (int pass = 0; pass < 28; ++pass) {     // 2*56*64 elems, lane = n
        int idx = pass*256 + t;
        int n = idx & 63;
        int rest = idx >> 6;                    // 0..111
        int pi = (rest >= 56) ? 1 : 0;
        int j = rest - 56*pi;
        int g = ((i0 + pi)*OW + j)*64 + n;
        float uo = ub[g];
        float gram = ot[(pi*64 + j)*65 + n];
        float un = uo + ETA * (bp[g] - uo - gram + softthr(uo));
        if (last) out[(((size_t)img*ATOMS + n)*OH + (i0 + pi))*OW + j] = softthr(un);
        else      up[g] = un;
    }
}

extern "C" void kernel_launch(void* const* d_in, const int* in_sizes, int n_in,
                              void* d_out, int out_size, void* d_ws, size_t ws_size,
                              hipStream_t stream) {
    const float* x = (const float*)d_in[0];
    const float* D = (const float*)d_in[1];
    float* out = (float*)d_out;
    float* ws = (float*)d_ws;
    float* b  = ws;                        // NLAT f32 (channel-last)
    float* u0 = b  + NLAT;                 // NLAT f32
    float* u1 = u0 + NLAT;                 // NLAT f32
    float* DT = u1 + NLAT;                 // 12288 f32
    float* Gf = DT + 12288;                // 81*4096 f32
    unsigned short* GAh = (unsigned short*)(Gf + 331776);
    unsigned short* GAl = GAh + 331776;
    unsigned short* DAh = GAl + 331776;
    unsigned short* DAl = DAh + 12288;
    prep_dt_kernel<<<48, 256, 0, stream>>>(D, DT);
    prep_gram_kernel<<<1296, 256, 0, stream>>>(DT, Gf);
    prep_packg_kernel<<<162, 256, 0, stream>>>(Gf, GAh, GAl);
    prep_packd_kernel<<<6, 256, 0, stream>>>(D, DAh, DAl);
    conv_b_kernel<<<BATCH*49, 256, 0, stream>>>(x, DAh, DAl, b, u0);
    float* uin = u0; float* uo2 = u1;
    for (int it = 0; it < 9; ++it) {       // iterations 2..10 (iter 1 folded)
        int last = (it == 8);
        lca_iter_kernel<<<BATCH*28, 256, 0, stream>>>(b, uin, uo2, GAh, GAl, out, last);
        float* tmp = uin; uin = uo2; uo2 = tmp;
    }
}

// Round 7
// 1652.929 us; speedup vs baseline: 6.9496x; 1.1154x over previous
//
#include <hip/hip_runtime.h>

#define BATCH 64
#define ATOMS 64
#define CIN 3
#define KS 8
#define H 224
#define W 224
#define OH 56
#define OW 56
#define NLAT (BATCH*ATOMS*OH*OW)   // 12,845,056
#define IMGSZ (OH*OW*ATOMS)        // 200,704 elems per image (channel-last)
#define LAM 0.1f
#define ETA 0.1f

typedef __attribute__((ext_vector_type(8)))  __bf16    bf16x8;
typedef __attribute__((ext_vector_type(8)))  _Float16  f16x8;
typedef __attribute__((ext_vector_type(16))) float     floatx16;

union FragU { uint4 u; bf16x8 v; };
union FragH { uint4 u; f16x8 v; };
union HalfBits { _Float16 h; unsigned short s; };

__device__ __forceinline__ float softthr(float u) {
    float p = u - LAM;  p = p > 0.f ? p : 0.f;
    float q = -u - LAM; q = q > 0.f ? q : 0.f;
    return p - q;
}
__device__ __forceinline__ unsigned short f2bf(float f) {   // RNE
    union { float f; unsigned int u; } c; c.f = f;
    unsigned int r = c.u + 0x7fffu + ((c.u >> 16) & 1u);
    return (unsigned short)(r >> 16);
}
__device__ __forceinline__ float bf2f(unsigned short h) {
    union { unsigned int u; float f; } c; c.u = ((unsigned int)h) << 16;
    return c.f;
}
__device__ __forceinline__ unsigned short f2h(float f) {    // fp16 bits, RNE
    HalfBits hb; hb.h = (_Float16)f; return hb.s;
}
__device__ __forceinline__ float h2f(unsigned short s) {
    HalfBits hb; hb.s = s; return (float)hb.h;
}

// DT[((c*8+y)*8+x)*64 + m] = D[m,c,y,x]
__global__ void prep_dt_kernel(const float* __restrict__ D,
                               float* __restrict__ DT) {
    int idx = blockIdx.x * 256 + threadIdx.x;
    if (idx < CIN*KS*KS*ATOMS) {
        int m = idx & 63;
        int r = idx >> 6;
        int xk = r & 7, y = (r >> 3) & 7, c = r >> 6;
        DT[idx] = D[((m*CIN + c)*KS + y)*KS + xk];
    }
}

// 9 table-sets (inclusion-exclusion for boundary classes), 9 dpq each.
// tbl: 0=T0(all) 1=-dY1 2=-dY2 3=-dX1 4=-dX2 5=+dC11 6=+dC12 7=+dC21 8=+dC22
__global__ void prep_gram_kernel(const float* __restrict__ DT,
                                 float* __restrict__ G) {
    int blk = blockIdx.x;              // td*16 + nchunk
    int td = blk >> 4;
    int tbl = td / 9, dpq = td % 9;
    int dp = dpq / 3, dq = dpq % 3;
    int di = 1 - dp, dj = 1 - dq;
    int ylo = (0 > -4*di) ? 0 : -4*di;
    int yhi = (8 < 8-4*di) ? 8 : 8-4*di;
    int xlo = (0 > -4*dj) ? 0 : -4*dj;
    int xhi = (8 < 8-4*dj) ? 8 : 8-4*dj;
    if (tbl==1 || tbl==5 || tbl==6) { if (yhi > 2) yhi = 2; }
    if (tbl==2 || tbl==7 || tbl==8) { if (ylo < 6) ylo = 6; }
    if (tbl==3 || tbl==5 || tbl==7) { if (xhi > 2) xhi = 2; }
    if (tbl==4 || tbl==6 || tbl==8) { if (xlo < 6) xlo = 6; }
    float sign = (tbl >= 1 && tbl <= 4) ? -1.f : 1.f;
    int t = threadIdx.x;
    int m = t & 63;
    int n = (blk & 15)*4 + (t >> 6);
    float s = 0.f;
    for (int c = 0; c < CIN; ++c)
        for (int y = ylo; y < yhi; ++y)
            for (int x = xlo; x < xhi; ++x)
                s += DT[((c*8+y)*8+x)*64 + m] *
                     DT[((c*8+y+4*di)*8 + (x+4*dj))*64 + n];
    G[td*4096 + n*64 + m] = sign * s;
}

// Pack G into MFMA A-operand layout, split FP16 hi/lo.
__global__ void prep_packg_kernel(const float* __restrict__ G,
                                  unsigned short* __restrict__ GAh,
                                  unsigned short* __restrict__ GAl) {
    int g = blockIdx.x * 256 + threadIdx.x;      // 162*256 = 41472 groups
    int lane = g & 63;
    int r = g >> 6;
    int kstep = r & 3; r >>= 2;
    int mhalf = r & 1; int td = r >> 1;          // tbl*9+dpq
    int m = mhalf*32 + (lane & 31);
    int n = kstep*16 + (lane >> 5)*8;
    const float* src = G + td*4096 + n*64 + m;
#pragma unroll
    for (int j = 0; j < 8; ++j) {
        float v = src[j*64];
        unsigned short h = f2h(v);
        GAh[g*8 + j] = h;
        GAl[g*8 + j] = f2h(v - h2f(h));
    }
}

// Pack D into MFMA A-layout for conv_b: K=192, k = c*64+y*8+x. (bf16 split)
__global__ void prep_packd_kernel(const float* __restrict__ D,
                                  unsigned short* __restrict__ DAh,
                                  unsigned short* __restrict__ DAl) {
    int g = blockIdx.x * 256 + threadIdx.x;
    if (g >= 1536) return;
    int lane = g & 63;
    int r = g >> 6;
    int kstep = r % 12, mhalf = r / 12;
    int m = mhalf*32 + (lane & 31);
    int k0 = kstep*16 + (lane >> 5)*8;
#pragma unroll
    for (int j = 0; j < 8; ++j) {
        float v = D[m*192 + k0 + j];
        unsigned short h = f2bf(v);
        DAh[g*8 + j] = h;
        DAl[g*8 + j] = f2bf(v - bf2f(h));
    }
}

// b = conv2d(x, D, stride4, pad2); u = 0.1*b. Output CHANNEL-LAST [i][j][n].
__global__ __launch_bounds__(256) void conv_b_kernel(
        const float* __restrict__ x,
        const unsigned short* __restrict__ DAh,
        const unsigned short* __restrict__ DAl,
        float* __restrict__ b, float* __restrict__ u) {
    __shared__ __align__(16) unsigned short xth[CIN*36*36];
    __shared__ __align__(16) unsigned short xtl[CIN*36*36];
    __shared__ float ot[64*65];
    int blk = blockIdx.x;
    int img = blk / 49, tile = blk % 49;
    int i0 = (tile / 7) * 8, j0 = (tile % 7) * 8;
    int t = threadIdx.x;
    int r0 = 4*i0 - 2, c0 = 4*j0 - 2;
    for (int f = t; f < CIN*36*36; f += 256) {
        int cc = f / 1296, rem = f % 1296;
        int rr = rem / 36, qq = rem % 36;
        int Y = r0 + rr, X = c0 + qq;
        float v = 0.f;
        if (Y >= 0 && Y < H && X >= 0 && X < W)
            v = x[((img*CIN + cc)*H + Y)*W + X];
        unsigned short h = f2bf(v);
        xth[f] = h;
        xtl[f] = f2bf(v - bf2f(h));
    }
    __syncthreads();
    int lane = t & 63, wave = t >> 6;
    int mhalf = wave & 1, poshalf = wave >> 1;
    int pos = poshalf*32 + (lane & 31), pi = pos >> 3, pj = pos & 7;
    int khalf = lane >> 5;
    floatx16 acc;
#pragma unroll
    for (int i = 0; i < 16; ++i) acc[i] = 0.f;
    const uint4* Ah4 = (const uint4*)DAh;
    const uint4* Al4 = (const uint4*)DAl;
#pragma unroll 3
    for (int kstep = 0; kstep < 12; ++kstep) {
        int k0 = kstep*16 + khalf*8;
        int cc = k0 >> 6, yy = (k0 >> 3) & 7;
        int boff = cc*1296 + (4*pi + yy)*36 + 4*pj;
        FragU ah, al, bh, bl;
        ah.u = Ah4[(mhalf*12 + kstep)*64 + lane];
        al.u = Al4[(mhalf*12 + kstep)*64 + lane];
        const uint2* ph = (const uint2*)(xth + boff);
        uint2 h0 = ph[0], h1 = ph[1];
        bh.u = make_uint4(h0.x, h0.y, h1.x, h1.y);
        const uint2* pl = (const uint2*)(xtl + boff);
        uint2 l0 = pl[0], l1 = pl[1];
        bl.u = make_uint4(l0.x, l0.y, l1.x, l1.y);
        acc = __builtin_amdgcn_mfma_f32_32x32x16_bf16(ah.v, bh.v, acc, 0, 0, 0);
        acc = __builtin_amdgcn_mfma_f32_32x32x16_bf16(ah.v, bl.v, acc, 0, 0, 0);
        acc = __builtin_amdgcn_mfma_f32_32x32x16_bf16(al.v, bh.v, acc, 0, 0, 0);
    }
#pragma unroll
    for (int r16 = 0; r16 < 16; ++r16) {
        int row = (r16 & 3) + 8*(r16 >> 2) + 4*khalf;
        ot[(mhalf*32 + row)*65 + pos] = acc[r16];
    }
    __syncthreads();
    // channel-last epilogue: lane = channel -> 256B contiguous stores
    int m = t & 63;
    float* bp = b + (size_t)img*IMGSZ;
    float* up = u + (size_t)img*IMGSZ;
#pragma unroll
    for (int e = 0; e < 16; ++e) {
        int pp = e*4 + (t >> 6);
        int gi = ((i0 + (pp >> 3))*OW + j0 + (pp & 7))*64 + m;
        float v = ot[m*65 + pp];
        bp[gi] = v;
        up[gi] = ETA * v;
    }
}

// One LCA step on a 2-row x 56-col band (channel-last state), FP16 GEMM.
// a-tile stored ONCE as fp16 (29.7 KB); G split hi/lo fp16 from L2.
// LDS 33.3 KB -> 4 blocks/CU. B-frags hoisted to VGPRs per (dq,kstep).
__global__ __launch_bounds__(256, 4) void lca_iter_kernel(
        const float* __restrict__ b, const float* __restrict__ uin,
        float* __restrict__ uout,
        const unsigned short* __restrict__ GAh,
        const unsigned short* __restrict__ GAl,
        float* __restrict__ out, int last) {
    __shared__ __align__(16) unsigned char smem[33280];   // max(29696, 33280)
    unsigned short* at2h = (unsigned short*)smem;         // [rc][swizzled n]
    int blk = blockIdx.x;
    int img = blk / 28, bandi = blk % 28;
    int i0 = bandi*2;
    int t = threadIdx.x;
    const float* ub = uin + (size_t)img*IMGSZ;
    // Phase 1: halo band (4 rows x 58 cols x 64 n) -> soft -> fp16 -> LDS.
    for (int idx = t; idx < 232*16; idx += 256) {
        int chunk = idx >> 4, f4 = idx & 15;
        int p = chunk / 58, q = chunk - 58*p;
        int gi = i0 - 1 + p, gj = q - 1;
        int n0 = f4 << 2;
        float4 v = make_float4(0.f, 0.f, 0.f, 0.f);
        if (gi >= 0 && gi < OH && gj >= 0 && gj < OW)
            v = *(const float4*)(ub + ((gi*OW + gj)*64 + n0));
        ushort4 hv = make_ushort4(f2h(softthr(v.x)), f2h(softthr(v.y)),
                                  f2h(softthr(v.z)), f2h(softthr(v.w)));
        int kg = n0 >> 3;
        int base = chunk*64 + ((kg ^ (chunk & 7)) << 3) + (n0 & 7);
        *(ushort4*)(at2h + base) = hv;
    }
    __syncthreads();
    int lane = t & 63, wave = t >> 6;
    int mhalf = wave & 1, cgrp = wave >> 1;      // cgrp: pj 0..31 / 32..63
    int khalf = lane >> 5, cl = lane & 31;
    int pj = cgrp*32 + cl;
    int pjx = (pj < 56) ? pj : 0;                // clamp invalid columns
    floatx16 acc0, acc1;
#pragma unroll
    for (int i = 0; i < 16; ++i) { acc0[i] = 0.f; acc1[i] = 0.f; }
    const uint4* Gh4 = (const uint4*)GAh;
    const uint4* Gl4 = (const uint4*)GAl;
    const uint4* B4h = (const uint4*)at2h;
    int tbx = (cgrp == 0) ? 3 : 4;               // X boundary table
    unsigned msel = (cl == ((cgrp == 0) ? 0 : 23)) ? 0xFFFFFFFFu : 0u;
    int ymask = 0, tby = 0, tbc = 0;             // Y/corner (edge bands)
    if (bandi == 0)  { ymask = 1; tby = 1; tbc = (cgrp == 0) ? 5 : 6; }
    if (bandi == 27) { ymask = 2; tby = 2; tbc = (cgrp == 0) ? 7 : 8; }
    for (int dq = 0; dq < 3; ++dq) {
        for (int kstep = 0; kstep < 4; ++kstep) {
            int kg2 = kstep*2 + khalf;
            FragH bh[4];
#pragma unroll
            for (int p = 0; p < 4; ++p) {
                int rc = p*58 + pjx + dq;
                int slot = kg2 ^ (rc & 7);
                bh[p].u = B4h[rc*8 + slot];
            }
#pragma unroll
            for (int dp = 0; dp < 3; ++dp) {
                int dpq = 3*dp + dq;
                FragH ah, al, ax, bm0, bm1;
                ah.u = Gh4[((dpq*2 + mhalf)*4 + kstep)*64 + lane];
                al.u = Gl4[((dpq*2 + mhalf)*4 + kstep)*64 + lane];
                ax.u = Gh4[(((tbx*9 + dpq)*2 + mhalf)*4 + kstep)*64 + lane];
                bm0.u = make_uint4(bh[dp].u.x & msel, bh[dp].u.y & msel,
                                   bh[dp].u.z & msel, bh[dp].u.w & msel);
                bm1.u = make_uint4(bh[dp+1].u.x & msel, bh[dp+1].u.y & msel,
                                   bh[dp+1].u.z & msel, bh[dp+1].u.w & msel);
                acc0 = __builtin_amdgcn_mfma_f32_32x32x16_f16(ah.v, bh[dp].v, acc0, 0,0,0);
                acc0 = __builtin_amdgcn_mfma_f32_32x32x16_f16(al.v, bh[dp].v, acc0, 0,0,0);
                acc0 = __builtin_amdgcn_mfma_f32_32x32x16_f16(ax.v, bm0.v, acc0, 0,0,0);
                acc1 = __builtin_amdgcn_mfma_f32_32x32x16_f16(ah.v, bh[dp+1].v, acc1, 0,0,0);
                acc1 = __builtin_amdgcn_mfma_f32_32x32x16_f16(al.v, bh[dp+1].v, acc1, 0,0,0);
                acc1 = __builtin_amdgcn_mfma_f32_32x32x16_f16(ax.v, bm1.v, acc1, 0,0,0);
                if (ymask == 1) {
                    FragH ayh, ayl, ac;
                    ayh.u = Gh4[(((tby*9 + dpq)*2 + mhalf)*4 + kstep)*64 + lane];
                    ayl.u = Gl4[(((tby*9 + dpq)*2 + mhalf)*4 + kstep)*64 + lane];
                    ac.u  = Gh4[(((tbc*9 + dpq)*2 + mhalf)*4 + kstep)*64 + lane];
                    acc0 = __builtin_amdgcn_mfma_f32_32x32x16_f16(ayh.v, bh[dp].v, acc0, 0,0,0);
                    acc0 = __builtin_amdgcn_mfma_f32_32x32x16_f16(ayl.v, bh[dp].v, acc0, 0,0,0);
                    acc0 = __builtin_amdgcn_mfma_f32_32x32x16_f16(ac.v, bm0.v, acc0, 0,0,0);
                } else if (ymask == 2) {
                    FragH ayh, ayl, ac;
                    ayh.u = Gh4[(((tby*9 + dpq)*2 + mhalf)*4 + kstep)*64 + lane];
                    ayl.u = Gl4[(((tby*9 + dpq)*2 + mhalf)*4 + kstep)*64 + lane];
                    ac.u  = Gh4[(((tbc*9 + dpq)*2 + mhalf)*4 + kstep)*64 + lane];
                    acc1 = __builtin_amdgcn_mfma_f32_32x32x16_f16(ayh.v, bh[dp+1].v, acc1, 0,0,0);
                    acc1 = __builtin_amdgcn_mfma_f32_32x32x16_f16(ayl.v, bh[dp+1].v, acc1, 0,0,0);
                    acc1 = __builtin_amdgcn_mfma_f32_32x32x16_f16(ac.v, bm1.v, acc1, 0,0,0);
                }
            }
        }
    }
    __syncthreads();                   // at2 dead; overlay fp32 ot[pos][m]
    float* ot = (float*)smem;          // 128*65*4 = 33280 B
#pragma unroll
    for (int r16 = 0; r16 < 16; ++r16) {
        int row = (r16 & 3) + 8*(r16 >> 2) + 4*khalf;
        int m = mhalf*32 + row;
        ot[pj*65 + m] = acc0[r16];
        ot[(64 + pj)*65 + m] = acc1[r16];
    }
    __syncthreads();
    const float* bp = b + (size_t)img*IMGSZ;
    float* up = uout + (size_t)img*IMGSZ;
#pragma unroll 4
    for (int pass = 0; pass < 28; ++pass) {     // 2*56*64 elems, lane = n
        int idx = pass*256 + t;
        int n = idx & 63;
        int rest = idx >> 6;                    // 0..111
        int pi = (rest >= 56) ? 1 : 0;
        int j = rest - 56*pi;
        int g = ((i0 + pi)*OW + j)*64 + n;
        float uo = ub[g];
        float gram = ot[(pi*64 + j)*65 + n];
        float un = uo + ETA * (bp[g] - uo - gram + softthr(uo));
        if (last) out[(((size_t)img*ATOMS + n)*OH + (i0 + pi))*OW + j] = softthr(un);
        else      up[g] = un;
    }
}

extern "C" void kernel_launch(void* const* d_in, const int* in_sizes, int n_in,
                              void* d_out, int out_size, void* d_ws, size_t ws_size,
                              hipStream_t stream) {
    const float* x = (const float*)d_in[0];
    const float* D = (const float*)d_in[1];
    float* out = (float*)d_out;
    float* ws = (float*)d_ws;
    float* b  = ws;                        // NLAT f32 (channel-last)
    float* u0 = b  + NLAT;                 // NLAT f32
    float* u1 = u0 + NLAT;                 // NLAT f32
    float* DT = u1 + NLAT;                 // 12288 f32
    float* Gf = DT + 12288;                // 81*4096 f32
    unsigned short* GAh = (unsigned short*)(Gf + 331776);
    unsigned short* GAl = GAh + 331776;
    unsigned short* DAh = GAl + 331776;
    unsigned short* DAl = DAh + 12288;
    prep_dt_kernel<<<48, 256, 0, stream>>>(D, DT);
    prep_gram_kernel<<<1296, 256, 0, stream>>>(DT, Gf);
    prep_packg_kernel<<<162, 256, 0, stream>>>(Gf, GAh, GAl);
    prep_packd_kernel<<<6, 256, 0, stream>>>(D, DAh, DAl);
    conv_b_kernel<<<BATCH*49, 256, 0, stream>>>(x, DAh, DAl, b, u0);
    float* uin = u0; float* uo2 = u1;
    for (int it = 0; it < 9; ++it) {       // iterations 2..10 (iter 1 folded)
        int last = (it == 8);
        lca_iter_kernel<<<BATCH*28, 256, 0, stream>>>(b, uin, uo2, GAh, GAl, out, last);
        float* tmp = uin; uin = uo2; uo2 = tmp;
    }
}

// Round 8
// 1533.605 us; speedup vs baseline: 7.4903x; 1.0778x over previous
//
#include <hip/hip_runtime.h>

#define BATCH 64
#define ATOMS 64
#define CIN 3
#define KS 8
#define H 224
#define W 224
#define OH 56
#define OW 56
#define NLAT (BATCH*ATOMS*OH*OW)   // 12,845,056
#define IMGSZ (OH*OW*ATOMS)        // 200,704 elems per image (channel-last)
#define LAM 0.1f
#define ETA 0.1f

typedef __attribute__((ext_vector_type(8)))  __bf16    bf16x8;
typedef __attribute__((ext_vector_type(8)))  _Float16  f16x8;
typedef __attribute__((ext_vector_type(16))) float     floatx16;

union FragU { uint4 u; bf16x8 v; };
union FragH { uint4 u; f16x8 v; };
union HalfBits { _Float16 h; unsigned short s; };

__device__ __forceinline__ float softthr(float u) {
    float p = u - LAM;  p = p > 0.f ? p : 0.f;
    float q = -u - LAM; q = q > 0.f ? q : 0.f;
    return p - q;
}
__device__ __forceinline__ unsigned short f2bf(float f) {   // RNE
    union { float f; unsigned int u; } c; c.f = f;
    unsigned int r = c.u + 0x7fffu + ((c.u >> 16) & 1u);
    return (unsigned short)(r >> 16);
}
__device__ __forceinline__ float bf2f(unsigned short h) {
    union { unsigned int u; float f; } c; c.u = ((unsigned int)h) << 16;
    return c.f;
}
__device__ __forceinline__ unsigned short f2h(float f) {    // fp16 bits, RNE
    HalfBits hb; hb.h = (_Float16)f; return hb.s;
}
__device__ __forceinline__ float h2f(unsigned short s) {
    HalfBits hb; hb.s = s; return (float)hb.h;
}

// DT[((c*8+y)*8+x)*64 + m] = D[m,c,y,x]
__global__ void prep_dt_kernel(const float* __restrict__ D,
                               float* __restrict__ DT) {
    int idx = blockIdx.x * 256 + threadIdx.x;
    if (idx < CIN*KS*KS*ATOMS) {
        int m = idx & 63;
        int r = idx >> 6;
        int xk = r & 7, y = (r >> 3) & 7, c = r >> 6;
        DT[idx] = D[((m*CIN + c)*KS + y)*KS + xk];
    }
}

// 9 table-sets (inclusion-exclusion for boundary classes), 9 dpq each.
// tbl: 0=T0(all) 1=-dY1 2=-dY2 3=-dX1 4=-dX2 5=+dC11 6=+dC12 7=+dC21 8=+dC22
__global__ void prep_gram_kernel(const float* __restrict__ DT,
                                 float* __restrict__ G) {
    int blk = blockIdx.x;              // td*16 + nchunk
    int td = blk >> 4;
    int tbl = td / 9, dpq = td % 9;
    int dp = dpq / 3, dq = dpq % 3;
    int di = 1 - dp, dj = 1 - dq;
    int ylo = (0 > -4*di) ? 0 : -4*di;
    int yhi = (8 < 8-4*di) ? 8 : 8-4*di;
    int xlo = (0 > -4*dj) ? 0 : -4*dj;
    int xhi = (8 < 8-4*dj) ? 8 : 8-4*dj;
    if (tbl==1 || tbl==5 || tbl==6) { if (yhi > 2) yhi = 2; }
    if (tbl==2 || tbl==7 || tbl==8) { if (ylo < 6) ylo = 6; }
    if (tbl==3 || tbl==5 || tbl==7) { if (xhi > 2) xhi = 2; }
    if (tbl==4 || tbl==6 || tbl==8) { if (xlo < 6) xlo = 6; }
    float sign = (tbl >= 1 && tbl <= 4) ? -1.f : 1.f;
    int t = threadIdx.x;
    int m = t & 63;
    int n = (blk & 15)*4 + (t >> 6);
    float s = 0.f;
    for (int c = 0; c < CIN; ++c)
        for (int y = ylo; y < yhi; ++y)
            for (int x = xlo; x < xhi; ++x)
                s += DT[((c*8+y)*8+x)*64 + m] *
                     DT[((c*8+y+4*di)*8 + (x+4*dj))*64 + n];
    G[td*4096 + n*64 + m] = sign * s;
}

// Pack G into MFMA A-operand layout, split FP16 hi/lo.
__global__ void prep_packg_kernel(const float* __restrict__ G,
                                  unsigned short* __restrict__ GAh,
                                  unsigned short* __restrict__ GAl) {
    int g = blockIdx.x * 256 + threadIdx.x;      // 162*256 = 41472 groups
    int lane = g & 63;
    int r = g >> 6;
    int kstep = r & 3; r >>= 2;
    int mhalf = r & 1; int td = r >> 1;          // tbl*9+dpq
    int m = mhalf*32 + (lane & 31);
    int n = kstep*16 + (lane >> 5)*8;
    const float* src = G + td*4096 + n*64 + m;
#pragma unroll
    for (int j = 0; j < 8; ++j) {
        float v = src[j*64];
        unsigned short h = f2h(v);
        GAh[g*8 + j] = h;
        GAl[g*8 + j] = f2h(v - h2f(h));
    }
}

// Pack D into MFMA A-layout for conv_b: K=192, k = c*64+y*8+x. (bf16 split)
__global__ void prep_packd_kernel(const float* __restrict__ D,
                                  unsigned short* __restrict__ DAh,
                                  unsigned short* __restrict__ DAl) {
    int g = blockIdx.x * 256 + threadIdx.x;
    if (g >= 1536) return;
    int lane = g & 63;
    int r = g >> 6;
    int kstep = r % 12, mhalf = r / 12;
    int m = mhalf*32 + (lane & 31);
    int k0 = kstep*16 + (lane >> 5)*8;
#pragma unroll
    for (int j = 0; j < 8; ++j) {
        float v = D[m*192 + k0 + j];
        unsigned short h = f2bf(v);
        DAh[g*8 + j] = h;
        DAl[g*8 + j] = f2bf(v - bf2f(h));
    }
}

// b = conv2d(x, D, stride4, pad2); u = 0.1*b. Output CHANNEL-LAST [i][j][n].
__global__ __launch_bounds__(256) void conv_b_kernel(
        const float* __restrict__ x,
        const unsigned short* __restrict__ DAh,
        const unsigned short* __restrict__ DAl,
        float* __restrict__ b, float* __restrict__ u) {
    __shared__ __align__(16) unsigned short xth[CIN*36*36];
    __shared__ __align__(16) unsigned short xtl[CIN*36*36];
    __shared__ float ot[64*65];
    int blk = blockIdx.x;
    int img = blk / 49, tile = blk % 49;
    int i0 = (tile / 7) * 8, j0 = (tile % 7) * 8;
    int t = threadIdx.x;
    int r0 = 4*i0 - 2, c0 = 4*j0 - 2;
    for (int f = t; f < CIN*36*36; f += 256) {
        int cc = f / 1296, rem = f % 1296;
        int rr = rem / 36, qq = rem % 36;
        int Y = r0 + rr, X = c0 + qq;
        float v = 0.f;
        if (Y >= 0 && Y < H && X >= 0 && X < W)
            v = x[((img*CIN + cc)*H + Y)*W + X];
        unsigned short h = f2bf(v);
        xth[f] = h;
        xtl[f] = f2bf(v - bf2f(h));
    }
    __syncthreads();
    int lane = t & 63, wave = t >> 6;
    int mhalf = wave & 1, poshalf = wave >> 1;
    int pos = poshalf*32 + (lane & 31), pi = pos >> 3, pj = pos & 7;
    int khalf = lane >> 5;
    floatx16 acc;
#pragma unroll
    for (int i = 0; i < 16; ++i) acc[i] = 0.f;
    const uint4* Ah4 = (const uint4*)DAh;
    const uint4* Al4 = (const uint4*)DAl;
#pragma unroll 3
    for (int kstep = 0; kstep < 12; ++kstep) {
        int k0 = kstep*16 + khalf*8;
        int cc = k0 >> 6, yy = (k0 >> 3) & 7;
        int boff = cc*1296 + (4*pi + yy)*36 + 4*pj;
        FragU ah, al, bh, bl;
        ah.u = Ah4[(mhalf*12 + kstep)*64 + lane];
        al.u = Al4[(mhalf*12 + kstep)*64 + lane];
        const uint2* ph = (const uint2*)(xth + boff);
        uint2 h0 = ph[0], h1 = ph[1];
        bh.u = make_uint4(h0.x, h0.y, h1.x, h1.y);
        const uint2* pl = (const uint2*)(xtl + boff);
        uint2 l0 = pl[0], l1 = pl[1];
        bl.u = make_uint4(l0.x, l0.y, l1.x, l1.y);
        acc = __builtin_amdgcn_mfma_f32_32x32x16_bf16(ah.v, bh.v, acc, 0, 0, 0);
        acc = __builtin_amdgcn_mfma_f32_32x32x16_bf16(ah.v, bl.v, acc, 0, 0, 0);
        acc = __builtin_amdgcn_mfma_f32_32x32x16_bf16(al.v, bh.v, acc, 0, 0, 0);
    }
#pragma unroll
    for (int r16 = 0; r16 < 16; ++r16) {
        int row = (r16 & 3) + 8*(r16 >> 2) + 4*khalf;
        ot[(mhalf*32 + row)*65 + pos] = acc[r16];
    }
    __syncthreads();
    // channel-last epilogue: lane = channel -> 256B contiguous stores
    int m = t & 63;
    float* bp = b + (size_t)img*IMGSZ;
    float* up = u + (size_t)img*IMGSZ;
#pragma unroll
    for (int e = 0; e < 16; ++e) {
        int pp = e*4 + (t >> 6);
        int gi = ((i0 + (pp >> 3))*OW + j0 + (pp & 7))*64 + m;
        float v = ot[m*65 + pp];
        bp[gi] = v;
        up[gi] = ETA * v;
    }
}

// One LCA step on a 2-row x 56-col band (channel-last state), FP16 GEMM.
// Low-register structure: per (dq,kstep) hoist 4 B-row frags; then a short
// TERM loop (T0h, T0l, Tx-masked [+ Tyh, Tyl, Tc-masked on edge bands]),
// each loading one A-frag at a time. Peak live ~60 regs -> no scratch
// spills at 4 blocks/CU (R7's WRITE_SIZE blowup was spill traffic).
__global__ __launch_bounds__(256, 4) void lca_iter_kernel(
        const float* __restrict__ b, const float* __restrict__ uin,
        float* __restrict__ uout,
        const unsigned short* __restrict__ GAh,
        const unsigned short* __restrict__ GAl,
        float* __restrict__ out, int last) {
    __shared__ __align__(16) unsigned char smem[33280];   // max(29696, 33280)
    unsigned short* at2h = (unsigned short*)smem;         // [rc][swizzled n]
    int blk = blockIdx.x;
    int img = blk / 28, bandi = blk % 28;
    int i0 = bandi*2;
    int t = threadIdx.x;
    const float* ub = uin + (size_t)img*IMGSZ;
    // Phase 1: halo band (4 rows x 58 cols x 64 n) -> soft -> fp16 -> LDS.
    for (int idx = t; idx < 232*16; idx += 256) {
        int chunk = idx >> 4, f4 = idx & 15;
        int p = chunk / 58, q = chunk - 58*p;
        int gi = i0 - 1 + p, gj = q - 1;
        int n0 = f4 << 2;
        float4 v = make_float4(0.f, 0.f, 0.f, 0.f);
        if (gi >= 0 && gi < OH && gj >= 0 && gj < OW)
            v = *(const float4*)(ub + ((gi*OW + gj)*64 + n0));
        ushort4 hv = make_ushort4(f2h(softthr(v.x)), f2h(softthr(v.y)),
                                  f2h(softthr(v.z)), f2h(softthr(v.w)));
        int kg = n0 >> 3;
        int base = chunk*64 + ((kg ^ (chunk & 7)) << 3) + (n0 & 7);
        *(ushort4*)(at2h + base) = hv;
    }
    __syncthreads();
    int lane = t & 63, wave = t >> 6;
    int mhalf = wave & 1, cgrp = wave >> 1;      // cgrp: pj 0..31 / 32..63
    int khalf = lane >> 5, cl = lane & 31;
    int pj = cgrp*32 + cl;
    int pjx = (pj < 56) ? pj : 0;                // clamp invalid columns
    floatx16 acc0, acc1;
#pragma unroll
    for (int i = 0; i < 16; ++i) { acc0[i] = 0.f; acc1[i] = 0.f; }
    const uint4* Gh4 = (const uint4*)GAh;
    const uint4* Gl4 = (const uint4*)GAl;
    const uint4* B4h = (const uint4*)at2h;
    int tbx = (cgrp == 0) ? 3 : 4;               // X boundary table
    unsigned msel = (cl == ((cgrp == 0) ? 0 : 23)) ? 0xFFFFFFFFu : 0u;
    int ymask = 0, tby = 0, tbc = 0;             // Y/corner (edge bands)
    int nt = 3;
    if (bandi == 0)  { ymask = 1; tby = 1; tbc = (cgrp == 0) ? 5 : 6; nt = 6; }
    if (bandi == 27) { ymask = 2; tby = 2; tbc = (cgrp == 0) ? 7 : 8; nt = 6; }
    for (int dq = 0; dq < 3; ++dq) {
        for (int kstep = 0; kstep < 4; ++kstep) {
            int kg2 = kstep*2 + khalf;
            FragH B[4];
#pragma unroll
            for (int p = 0; p < 4; ++p) {
                int rc = p*58 + pjx + dq;
                B[p].u = B4h[rc*8 + (kg2 ^ (rc & 7))];
            }
            for (int tm = 0; tm < nt; ++tm) {
                int td = (tm < 2) ? 0 : (tm == 2) ? tbx : (tm < 5) ? tby : tbc;
                const uint4* Ap = ((tm == 1) || (tm == 4)) ? Gl4 : Gh4;
                bool masked = (tm == 2) || (tm == 5);
                int am = (tm < 3) ? 3 : ymask;
#pragma unroll
                for (int dp = 0; dp < 3; ++dp) {
                    FragH a;
                    a.u = Ap[(((td*9 + 3*dp + dq)*2 + mhalf)*4 + kstep)*64 + lane];
                    if (!masked) {
                        if (am & 1)
                            acc0 = __builtin_amdgcn_mfma_f32_32x32x16_f16(a.v, B[dp].v, acc0, 0,0,0);
                        if (am & 2)
                            acc1 = __builtin_amdgcn_mfma_f32_32x32x16_f16(a.v, B[dp+1].v, acc1, 0,0,0);
                    } else {
                        if (am & 1) {
                            FragH bm;
                            bm.u = make_uint4(B[dp].u.x & msel, B[dp].u.y & msel,
                                              B[dp].u.z & msel, B[dp].u.w & msel);
                            acc0 = __builtin_amdgcn_mfma_f32_32x32x16_f16(a.v, bm.v, acc0, 0,0,0);
                        }
                        if (am & 2) {
                            FragH bm;
                            bm.u = make_uint4(B[dp+1].u.x & msel, B[dp+1].u.y & msel,
                                              B[dp+1].u.z & msel, B[dp+1].u.w & msel);
                            acc1 = __builtin_amdgcn_mfma_f32_32x32x16_f16(a.v, bm.v, acc1, 0,0,0);
                        }
                    }
                }
            }
        }
    }
    __syncthreads();                   // at2 dead; overlay fp32 ot[pos][m]
    float* ot = (float*)smem;          // 128*65*4 = 33280 B
#pragma unroll
    for (int r16 = 0; r16 < 16; ++r16) {
        int row = (r16 & 3) + 8*(r16 >> 2) + 4*khalf;
        int m = mhalf*32 + row;
        ot[pj*65 + m] = acc0[r16];
        ot[(64 + pj)*65 + m] = acc1[r16];
    }
    __syncthreads();
    const float* bp = b + (size_t)img*IMGSZ;
    float* up = uout + (size_t)img*IMGSZ;
#pragma unroll 4
    for (int pass = 0; pass < 28; ++pass) {     // 2*56*64 elems, lane = n
        int idx = pass*256 + t;
        int n = idx & 63;
        int rest = idx >> 6;                    // 0..111
        int pi = (rest >= 56) ? 1 : 0;
        int j = rest - 56*pi;
        int g = ((i0 + pi)*OW + j)*64 + n;
        float uo = ub[g];
        float gram = ot[(pi*64 + j)*65 + n];
        float un = uo + ETA * (bp[g] - uo - gram + softthr(uo));
        if (last) out[(((size_t)img*ATOMS + n)*OH + (i0 + pi))*OW + j] = softthr(un);
        else      up[g] = un;
    }
}

extern "C" void kernel_launch(void* const* d_in, const int* in_sizes, int n_in,
                              void* d_out, int out_size, void* d_ws, size_t ws_size,
                              hipStream_t stream) {
    const float* x = (const float*)d_in[0];
    const float* D = (const float*)d_in[1];
    float* out = (float*)d_out;
    float* ws = (float*)d_ws;
    float* b  = ws;                        // NLAT f32 (channel-last)
    float* u0 = b  + NLAT;                 // NLAT f32
    float* u1 = u0 + NLAT;                 // NLAT f32
    float* DT = u1 + NLAT;                 // 12288 f32
    float* Gf = DT + 12288;                // 81*4096 f32
    unsigned short* GAh = (unsigned short*)(Gf + 331776);
    unsigned short* GAl = GAh + 331776;
    unsigned short* DAh = GAl + 331776;
    unsigned short* DAl = DAh + 12288;
    prep_dt_kernel<<<48, 256, 0, stream>>>(D, DT);
    prep_gram_kernel<<<1296, 256, 0, stream>>>(DT, Gf);
    prep_packg_kernel<<<162, 256, 0, stream>>>(Gf, GAh, GAl);
    prep_packd_kernel<<<6, 256, 0, stream>>>(D, DAh, DAl);
    conv_b_kernel<<<BATCH*49, 256, 0, stream>>>(x, DAh, DAl, b, u0);
    float* uin = u0; float* uo2 = u1;
    for (int it = 0; it < 9; ++it) {       // iterations 2..10 (iter 1 folded)
        int last = (it == 8);
        lca_iter_kernel<<<BATCH*28, 256, 0, stream>>>(b, uin, uo2, GAh, GAl, out, last);
        float* tmp = uin; uin = uo2; uo2 = tmp;
    }
}

// Round 9
// 1340.751 us; speedup vs baseline: 8.5677x; 1.1438x over previous
//
#include <hip/hip_runtime.h>

#define BATCH 64
#define ATOMS 64
#define CIN 3
#define KS 8
#define H 224
#define W 224
#define OH 56
#define OW 56
#define NLAT (BATCH*ATOMS*OH*OW)   // 12,845,056
#define IMGSZ (OH*OW*ATOMS)        // 200,704 elems per image (channel-last)
#define LAM 0.1f
#define ETA 0.1f

typedef __attribute__((ext_vector_type(8)))  __bf16    bf16x8;
typedef __attribute__((ext_vector_type(8)))  _Float16  f16x8;
typedef __attribute__((ext_vector_type(16))) float     floatx16;

union FragU { uint4 u; bf16x8 v; };
union FragH { uint4 u; f16x8 v; };
union HalfBits { _Float16 h; unsigned short s; };

__device__ __forceinline__ float softthr(float u) {
    float p = u - LAM;  p = p > 0.f ? p : 0.f;
    float q = -u - LAM; q = q > 0.f ? q : 0.f;
    return p - q;
}
__device__ __forceinline__ unsigned short f2bf(float f) {   // RNE
    union { float f; unsigned int u; } c; c.f = f;
    unsigned int r = c.u + 0x7fffu + ((c.u >> 16) & 1u);
    return (unsigned short)(r >> 16);
}
__device__ __forceinline__ float bf2f(unsigned short h) {
    union { unsigned int u; float f; } c; c.u = ((unsigned int)h) << 16;
    return c.f;
}
__device__ __forceinline__ unsigned short f2h(float f) {    // fp16 bits, RNE
    HalfBits hb; hb.h = (_Float16)f; return hb.s;
}
__device__ __forceinline__ float h2f(unsigned short s) {
    HalfBits hb; hb.s = s; return (float)hb.h;
}

// DT[((c*8+y)*8+x)*64 + m] = D[m,c,y,x]
__global__ void prep_dt_kernel(const float* __restrict__ D,
                               float* __restrict__ DT) {
    int idx = blockIdx.x * 256 + threadIdx.x;
    if (idx < CIN*KS*KS*ATOMS) {
        int m = idx & 63;
        int r = idx >> 6;
        int xk = r & 7, y = (r >> 3) & 7, c = r >> 6;
        DT[idx] = D[((m*CIN + c)*KS + y)*KS + xk];
    }
}

// 9 table-sets (inclusion-exclusion for boundary classes), 9 dpq each.
// tbl: 0=T0(all) 1=-dY1 2=-dY2 3=-dX1 4=-dX2 5=+dC11 6=+dC12 7=+dC21 8=+dC22
__global__ void prep_gram_kernel(const float* __restrict__ DT,
                                 float* __restrict__ G) {
    int blk = blockIdx.x;              // td*16 + nchunk
    int td = blk >> 4;
    int tbl = td / 9, dpq = td % 9;
    int dp = dpq / 3, dq = dpq % 3;
    int di = 1 - dp, dj = 1 - dq;
    int ylo = (0 > -4*di) ? 0 : -4*di;
    int yhi = (8 < 8-4*di) ? 8 : 8-4*di;
    int xlo = (0 > -4*dj) ? 0 : -4*dj;
    int xhi = (8 < 8-4*dj) ? 8 : 8-4*dj;
    if (tbl==1 || tbl==5 || tbl==6) { if (yhi > 2) yhi = 2; }
    if (tbl==2 || tbl==7 || tbl==8) { if (ylo < 6) ylo = 6; }
    if (tbl==3 || tbl==5 || tbl==7) { if (xhi > 2) xhi = 2; }
    if (tbl==4 || tbl==6 || tbl==8) { if (xlo < 6) xlo = 6; }
    float sign = (tbl >= 1 && tbl <= 4) ? -1.f : 1.f;
    int t = threadIdx.x;
    int m = t & 63;
    int n = (blk & 15)*4 + (t >> 6);
    float s = 0.f;
    for (int c = 0; c < CIN; ++c)
        for (int y = ylo; y < yhi; ++y)
            for (int x = xlo; x < xhi; ++x)
                s += DT[((c*8+y)*8+x)*64 + m] *
                     DT[((c*8+y+4*di)*8 + (x+4*dj))*64 + n];
    G[td*4096 + n*64 + m] = sign * s;
}

// Pack G into MFMA A-operand layout, split FP16 hi/lo.
__global__ void prep_packg_kernel(const float* __restrict__ G,
                                  unsigned short* __restrict__ GAh,
                                  unsigned short* __restrict__ GAl) {
    int g = blockIdx.x * 256 + threadIdx.x;      // 162*256 = 41472 groups
    int lane = g & 63;
    int r = g >> 6;
    int kstep = r & 3; r >>= 2;
    int mhalf = r & 1; int td = r >> 1;          // tbl*9+dpq
    int m = mhalf*32 + (lane & 31);
    int n = kstep*16 + (lane >> 5)*8;
    const float* src = G + td*4096 + n*64 + m;
#pragma unroll
    for (int j = 0; j < 8; ++j) {
        float v = src[j*64];
        unsigned short h = f2h(v);
        GAh[g*8 + j] = h;
        GAl[g*8 + j] = f2h(v - h2f(h));
    }
}

// Pack D into MFMA A-layout for conv_b: K=192, k = c*64+y*8+x. (bf16 split)
__global__ void prep_packd_kernel(const float* __restrict__ D,
                                  unsigned short* __restrict__ DAh,
                                  unsigned short* __restrict__ DAl) {
    int g = blockIdx.x * 256 + threadIdx.x;
    if (g >= 1536) return;
    int lane = g & 63;
    int r = g >> 6;
    int kstep = r % 12, mhalf = r / 12;
    int m = mhalf*32 + (lane & 31);
    int k0 = kstep*16 + (lane >> 5)*8;
#pragma unroll
    for (int j = 0; j < 8; ++j) {
        float v = D[m*192 + k0 + j];
        unsigned short h = f2bf(v);
        DAh[g*8 + j] = h;
        DAl[g*8 + j] = f2bf(v - bf2f(h));
    }
}

// b = conv2d(x, D, stride4, pad2); u = 0.1*b. Output CHANNEL-LAST [i][j][n].
__global__ __launch_bounds__(256) void conv_b_kernel(
        const float* __restrict__ x,
        const unsigned short* __restrict__ DAh,
        const unsigned short* __restrict__ DAl,
        float* __restrict__ b, float* __restrict__ u) {
    __shared__ __align__(16) unsigned short xth[CIN*36*36];
    __shared__ __align__(16) unsigned short xtl[CIN*36*36];
    __shared__ float ot[64*65];
    int blk = blockIdx.x;
    int img = blk / 49, tile = blk % 49;
    int i0 = (tile / 7) * 8, j0 = (tile % 7) * 8;
    int t = threadIdx.x;
    int r0 = 4*i0 - 2, c0 = 4*j0 - 2;
    for (int f = t; f < CIN*36*36; f += 256) {
        int cc = f / 1296, rem = f % 1296;
        int rr = rem / 36, qq = rem % 36;
        int Y = r0 + rr, X = c0 + qq;
        float v = 0.f;
        if (Y >= 0 && Y < H && X >= 0 && X < W)
            v = x[((img*CIN + cc)*H + Y)*W + X];
        unsigned short h = f2bf(v);
        xth[f] = h;
        xtl[f] = f2bf(v - bf2f(h));
    }
    __syncthreads();
    int lane = t & 63, wave = t >> 6;
    int mhalf = wave & 1, poshalf = wave >> 1;
    int pos = poshalf*32 + (lane & 31), pi = pos >> 3, pj = pos & 7;
    int khalf = lane >> 5;
    floatx16 acc;
#pragma unroll
    for (int i = 0; i < 16; ++i) acc[i] = 0.f;
    const uint4* Ah4 = (const uint4*)DAh;
    const uint4* Al4 = (const uint4*)DAl;
#pragma unroll 3
    for (int kstep = 0; kstep < 12; ++kstep) {
        int k0 = kstep*16 + khalf*8;
        int cc = k0 >> 6, yy = (k0 >> 3) & 7;
        int boff = cc*1296 + (4*pi + yy)*36 + 4*pj;
        FragU ah, al, bh, bl;
        ah.u = Ah4[(mhalf*12 + kstep)*64 + lane];
        al.u = Al4[(mhalf*12 + kstep)*64 + lane];
        const uint2* ph = (const uint2*)(xth + boff);
        uint2 h0 = ph[0], h1 = ph[1];
        bh.u = make_uint4(h0.x, h0.y, h1.x, h1.y);
        const uint2* pl = (const uint2*)(xtl + boff);
        uint2 l0 = pl[0], l1 = pl[1];
        bl.u = make_uint4(l0.x, l0.y, l1.x, l1.y);
        acc = __builtin_amdgcn_mfma_f32_32x32x16_bf16(ah.v, bh.v, acc, 0, 0, 0);
        acc = __builtin_amdgcn_mfma_f32_32x32x16_bf16(ah.v, bl.v, acc, 0, 0, 0);
        acc = __builtin_amdgcn_mfma_f32_32x32x16_bf16(al.v, bh.v, acc, 0, 0, 0);
    }
#pragma unroll
    for (int r16 = 0; r16 < 16; ++r16) {
        int row = (r16 & 3) + 8*(r16 >> 2) + 4*khalf;
        ot[(mhalf*32 + row)*65 + pos] = acc[r16];
    }
    __syncthreads();
    // channel-last epilogue: lane = channel -> 256B contiguous stores
    int m = t & 63;
    float* bp = b + (size_t)img*IMGSZ;
    float* up = u + (size_t)img*IMGSZ;
#pragma unroll
    for (int e = 0; e < 16; ++e) {
        int pp = e*4 + (t >> 6);
        int gi = ((i0 + (pp >> 3))*OW + j0 + (pp & 7))*64 + m;
        float v = ot[m*65 + pp];
        bp[gi] = v;
        up[gi] = ETA * v;
    }
}

// One LCA step on a 2-row x 56-col band (channel-last state), FP16 GEMM.
// Minimal-register structure: per (dq,kstep,dp) load only B0,B1 from LDS
// (8 VGPRs), then the term loop (T0h, T0l, Tx-masked [+Tyh,Tyl,Tc on edge
// bands]) loads one A-frag at a time. Peak live ~90 unified regs -> no
// scratch at 4 blocks/CU (R7/R8 WRITE blowup was B-array spill traffic).
__global__ __launch_bounds__(256, 4) void lca_iter_kernel(
        const float* __restrict__ b, const float* __restrict__ uin,
        float* __restrict__ uout,
        const unsigned short* __restrict__ GAh,
        const unsigned short* __restrict__ GAl,
        float* __restrict__ out, int last) {
    __shared__ __align__(16) unsigned char smem[33280];   // max(29696, 33280)
    unsigned short* at2h = (unsigned short*)smem;         // [rc][swizzled n]
    int blk = blockIdx.x;
    int img = blk / 28, bandi = blk % 28;
    int i0 = bandi*2;
    int t = threadIdx.x;
    const float* ub = uin + (size_t)img*IMGSZ;
    // Phase 1: halo band (4 rows x 58 cols x 64 n) -> soft -> fp16 -> LDS.
    for (int idx = t; idx < 232*16; idx += 256) {
        int chunk = idx >> 4, f4 = idx & 15;
        int p = chunk / 58, q = chunk - 58*p;
        int gi = i0 - 1 + p, gj = q - 1;
        int n0 = f4 << 2;
        float4 v = make_float4(0.f, 0.f, 0.f, 0.f);
        if (gi >= 0 && gi < OH && gj >= 0 && gj < OW)
            v = *(const float4*)(ub + ((gi*OW + gj)*64 + n0));
        ushort4 hv = make_ushort4(f2h(softthr(v.x)), f2h(softthr(v.y)),
                                  f2h(softthr(v.z)), f2h(softthr(v.w)));
        int kg = n0 >> 3;
        int base = chunk*64 + ((kg ^ (chunk & 7)) << 3) + (n0 & 7);
        *(ushort4*)(at2h + base) = hv;
    }
    __syncthreads();
    int lane = t & 63, wave = t >> 6;
    int mhalf = wave & 1, cgrp = wave >> 1;      // cgrp: pj 0..31 / 32..63
    int khalf = lane >> 5, cl = lane & 31;
    int pj = cgrp*32 + cl;
    int pjx = (pj < 56) ? pj : 0;                // clamp invalid columns
    floatx16 acc0, acc1;
#pragma unroll
    for (int i = 0; i < 16; ++i) { acc0[i] = 0.f; acc1[i] = 0.f; }
    const uint4* Gh4 = (const uint4*)GAh;
    const uint4* Gl4 = (const uint4*)GAl;
    const uint4* B4h = (const uint4*)at2h;
    int tbx = (cgrp == 0) ? 3 : 4;               // X boundary table
    unsigned msel = (cl == ((cgrp == 0) ? 0 : 23)) ? 0xFFFFFFFFu : 0u;
    int ymask = 0, tby = 0, tbc = 0;             // Y/corner (edge bands)
    int nt = 3;
    if (bandi == 0)  { ymask = 1; tby = 1; tbc = (cgrp == 0) ? 5 : 6; nt = 6; }
    if (bandi == 27) { ymask = 2; tby = 2; tbc = (cgrp == 0) ? 7 : 8; nt = 6; }
    for (int dq = 0; dq < 3; ++dq) {
        for (int kstep = 0; kstep < 4; ++kstep) {
            int kg2 = kstep*2 + khalf;
#pragma unroll
            for (int dp = 0; dp < 3; ++dp) {
                int rc0 = dp*58 + pjx + dq;
                int rc1 = rc0 + 58;
                FragH B0, B1;
                B0.u = B4h[rc0*8 + (kg2 ^ (rc0 & 7))];
                B1.u = B4h[rc1*8 + (kg2 ^ (rc1 & 7))];
                for (int tm = 0; tm < nt; ++tm) {
                    int td = (tm < 2) ? 0 : (tm == 2) ? tbx : (tm < 5) ? tby : tbc;
                    const uint4* Ap = ((tm == 1) || (tm == 4)) ? Gl4 : Gh4;
                    bool masked = (tm == 2) || (tm == 5);
                    int am = (tm < 3) ? 3 : ymask;
                    FragH a;
                    a.u = Ap[(((td*9 + 3*dp + dq)*2 + mhalf)*4 + kstep)*64 + lane];
                    if (!masked) {
                        if (am & 1)
                            acc0 = __builtin_amdgcn_mfma_f32_32x32x16_f16(a.v, B0.v, acc0, 0,0,0);
                        if (am & 2)
                            acc1 = __builtin_amdgcn_mfma_f32_32x32x16_f16(a.v, B1.v, acc1, 0,0,0);
                    } else {
                        if (am & 1) {
                            FragH bm;
                            bm.u = make_uint4(B0.u.x & msel, B0.u.y & msel,
                                              B0.u.z & msel, B0.u.w & msel);
                            acc0 = __builtin_amdgcn_mfma_f32_32x32x16_f16(a.v, bm.v, acc0, 0,0,0);
                        }
                        if (am & 2) {
                            FragH bm;
                            bm.u = make_uint4(B1.u.x & msel, B1.u.y & msel,
                                              B1.u.z & msel, B1.u.w & msel);
                            acc1 = __builtin_amdgcn_mfma_f32_32x32x16_f16(a.v, bm.v, acc1, 0,0,0);
                        }
                    }
                }
            }
        }
    }
    __syncthreads();                   // at2 dead; overlay fp32 ot[pos][m]
    float* ot = (float*)smem;          // 128*65*4 = 33280 B
#pragma unroll
    for (int r16 = 0; r16 < 16; ++r16) {
        int row = (r16 & 3) + 8*(r16 >> 2) + 4*khalf;
        int m = mhalf*32 + row;
        ot[pj*65 + m] = acc0[r16];
        ot[(64 + pj)*65 + m] = acc1[r16];
    }
    __syncthreads();
    const float* bp = b + (size_t)img*IMGSZ;
    float* up = uout + (size_t)img*IMGSZ;
#pragma unroll 4
    for (int pass = 0; pass < 28; ++pass) {     // 2*56*64 elems, lane = n
        int idx = pass*256 + t;
        int n = idx & 63;
        int rest = idx >> 6;                    // 0..111
        int pi = (rest >= 56) ? 1 : 0;
        int j = rest - 56*pi;
        int g = ((i0 + pi)*OW + j)*64 + n;
        float uo = ub[g];
        float gram = ot[(pi*64 + j)*65 + n];
        float un = uo + ETA * (bp[g] - uo - gram + softthr(uo));
        if (last) out[(((size_t)img*ATOMS + n)*OH + (i0 + pi))*OW + j] = softthr(un);
        else      up[g] = un;
    }
}

extern "C" void kernel_launch(void* const* d_in, const int* in_sizes, int n_in,
                              void* d_out, int out_size, void* d_ws, size_t ws_size,
                              hipStream_t stream) {
    const float* x = (const float*)d_in[0];
    const float* D = (const float*)d_in[1];
    float* out = (float*)d_out;
    float* ws = (float*)d_ws;
    float* b  = ws;                        // NLAT f32 (channel-last)
    float* u0 = b  + NLAT;                 // NLAT f32
    float* u1 = u0 + NLAT;                 // NLAT f32
    float* DT = u1 + NLAT;                 // 12288 f32
    float* Gf = DT + 12288;                // 81*4096 f32
    unsigned short* GAh = (unsigned short*)(Gf + 331776);
    unsigned short* GAl = GAh + 331776;
    unsigned short* DAh = GAl + 331776;
    unsigned short* DAl = DAh + 12288;
    prep_dt_kernel<<<48, 256, 0, stream>>>(D, DT);
    prep_gram_kernel<<<1296, 256, 0, stream>>>(DT, Gf);
    prep_packg_kernel<<<162, 256, 0, stream>>>(Gf, GAh, GAl);
    prep_packd_kernel<<<6, 256, 0, stream>>>(D, DAh, DAl);
    conv_b_kernel<<<BATCH*49, 256, 0, stream>>>(x, DAh, DAl, b, u0);
    float* uin = u0; float* uo2 = u1;
    for (int it = 0; it < 9; ++it) {       // iterations 2..10 (iter 1 folded)
        int last = (it == 8);
        lca_iter_kernel<<<BATCH*28, 256, 0, stream>>>(b, uin, uo2, GAh, GAl, out, last);
        float* tmp = uin; uin = uo2; uo2 = tmp;
    }
}

// Round 10
// 1259.029 us; speedup vs baseline: 9.1238x; 1.0649x over previous
//
#include <hip/hip_runtime.h>

#define BATCH 64
#define ATOMS 64
#define CIN 3
#define KS 8
#define H 224
#define W 224
#define OH 56
#define OW 56
#define NLAT (BATCH*ATOMS*OH*OW)   // 12,845,056
#define IMGSZ (OH*OW*ATOMS)        // 200,704 elems per image (channel-last)
#define LAM 0.1f
#define ETA 0.1f

typedef __attribute__((ext_vector_type(8)))  __bf16    bf16x8;
typedef __attribute__((ext_vector_type(8)))  _Float16  f16x8;
typedef __attribute__((ext_vector_type(16))) float     floatx16;

union FragU { uint4 u; bf16x8 v; };
union FragH { uint4 u; f16x8 v; };
union HalfBits { _Float16 h; unsigned short s; };

__device__ __forceinline__ float softthr(float u) {
    float p = u - LAM;  p = p > 0.f ? p : 0.f;
    float q = -u - LAM; q = q > 0.f ? q : 0.f;
    return p - q;
}
__device__ __forceinline__ unsigned short f2bf(float f) {   // RNE
    union { float f; unsigned int u; } c; c.f = f;
    unsigned int r = c.u + 0x7fffu + ((c.u >> 16) & 1u);
    return (unsigned short)(r >> 16);
}
__device__ __forceinline__ float bf2f(unsigned short h) {
    union { unsigned int u; float f; } c; c.u = ((unsigned int)h) << 16;
    return c.f;
}
__device__ __forceinline__ unsigned short f2h(float f) {    // fp16 bits, RNE
    HalfBits hb; hb.h = (_Float16)f; return hb.s;
}
__device__ __forceinline__ float h2f(unsigned short s) {
    HalfBits hb; hb.s = s; return (float)hb.h;
}

// DT[((c*8+y)*8+x)*64 + m] = D[m,c,y,x]
__global__ void prep_dt_kernel(const float* __restrict__ D,
                               float* __restrict__ DT) {
    int idx = blockIdx.x * 256 + threadIdx.x;
    if (idx < CIN*KS*KS*ATOMS) {
        int m = idx & 63;
        int r = idx >> 6;
        int xk = r & 7, y = (r >> 3) & 7, c = r >> 6;
        DT[idx] = D[((m*CIN + c)*KS + y)*KS + xk];
    }
}

// 9 table-sets (inclusion-exclusion for boundary classes), 9 dpq each.
// tbl: 0=T0(all) 1=-dY1 2=-dY2 3=-dX1 4=-dX2 5=+dC11 6=+dC12 7=+dC21 8=+dC22
__global__ void prep_gram_kernel(const float* __restrict__ DT,
                                 float* __restrict__ G) {
    int blk = blockIdx.x;              // td*16 + nchunk
    int td = blk >> 4;
    int tbl = td / 9, dpq = td % 9;
    int dp = dpq / 3, dq = dpq % 3;
    int di = 1 - dp, dj = 1 - dq;
    int ylo = (0 > -4*di) ? 0 : -4*di;
    int yhi = (8 < 8-4*di) ? 8 : 8-4*di;
    int xlo = (0 > -4*dj) ? 0 : -4*dj;
    int xhi = (8 < 8-4*dj) ? 8 : 8-4*dj;
    if (tbl==1 || tbl==5 || tbl==6) { if (yhi > 2) yhi = 2; }
    if (tbl==2 || tbl==7 || tbl==8) { if (ylo < 6) ylo = 6; }
    if (tbl==3 || tbl==5 || tbl==7) { if (xhi > 2) xhi = 2; }
    if (tbl==4 || tbl==6 || tbl==8) { if (xlo < 6) xlo = 6; }
    float sign = (tbl >= 1 && tbl <= 4) ? -1.f : 1.f;
    int t = threadIdx.x;
    int m = t & 63;
    int n = (blk & 15)*4 + (t >> 6);
    float s = 0.f;
    for (int c = 0; c < CIN; ++c)
        for (int y = ylo; y < yhi; ++y)
            for (int x = xlo; x < xhi; ++x)
                s += DT[((c*8+y)*8+x)*64 + m] *
                     DT[((c*8+y+4*di)*8 + (x+4*dj))*64 + n];
    G[td*4096 + n*64 + m] = sign * s;
}

// Pack G into MFMA A-operand layout, split FP16 hi/lo.
__global__ void prep_packg_kernel(const float* __restrict__ G,
                                  unsigned short* __restrict__ GAh,
                                  unsigned short* __restrict__ GAl) {
    int g = blockIdx.x * 256 + threadIdx.x;      // 162*256 = 41472 groups
    int lane = g & 63;
    int r = g >> 6;
    int kstep = r & 3; r >>= 2;
    int mhalf = r & 1; int td = r >> 1;          // tbl*9+dpq
    int m = mhalf*32 + (lane & 31);
    int n = kstep*16 + (lane >> 5)*8;
    const float* src = G + td*4096 + n*64 + m;
#pragma unroll
    for (int j = 0; j < 8; ++j) {
        float v = src[j*64];
        unsigned short h = f2h(v);
        GAh[g*8 + j] = h;
        GAl[g*8 + j] = f2h(v - h2f(h));
    }
}

// Pack D into MFMA A-layout for conv_b: K=192, k = c*64+y*8+x. (bf16 split)
__global__ void prep_packd_kernel(const float* __restrict__ D,
                                  unsigned short* __restrict__ DAh,
                                  unsigned short* __restrict__ DAl) {
    int g = blockIdx.x * 256 + threadIdx.x;
    if (g >= 1536) return;
    int lane = g & 63;
    int r = g >> 6;
    int kstep = r % 12, mhalf = r / 12;
    int m = mhalf*32 + (lane & 31);
    int k0 = kstep*16 + (lane >> 5)*8;
#pragma unroll
    for (int j = 0; j < 8; ++j) {
        float v = D[m*192 + k0 + j];
        unsigned short h = f2bf(v);
        DAh[g*8 + j] = h;
        DAl[g*8 + j] = f2bf(v - bf2f(h));
    }
}

// b = conv2d(x, D, stride4, pad2); u = 0.1*b. Output CHANNEL-LAST [i][j][n].
__global__ __launch_bounds__(256) void conv_b_kernel(
        const float* __restrict__ x,
        const unsigned short* __restrict__ DAh,
        const unsigned short* __restrict__ DAl,
        float* __restrict__ b, float* __restrict__ u) {
    __shared__ __align__(16) unsigned short xth[CIN*36*36];
    __shared__ __align__(16) unsigned short xtl[CIN*36*36];
    __shared__ float ot[64*65];
    int blk = blockIdx.x;
    int img = blk / 49, tile = blk % 49;
    int i0 = (tile / 7) * 8, j0 = (tile % 7) * 8;
    int t = threadIdx.x;
    int r0 = 4*i0 - 2, c0 = 4*j0 - 2;
    for (int f = t; f < CIN*36*36; f += 256) {
        int cc = f / 1296, rem = f % 1296;
        int rr = rem / 36, qq = rem % 36;
        int Y = r0 + rr, X = c0 + qq;
        float v = 0.f;
        if (Y >= 0 && Y < H && X >= 0 && X < W)
            v = x[((img*CIN + cc)*H + Y)*W + X];
        unsigned short h = f2bf(v);
        xth[f] = h;
        xtl[f] = f2bf(v - bf2f(h));
    }
    __syncthreads();
    int lane = t & 63, wave = t >> 6;
    int mhalf = wave & 1, poshalf = wave >> 1;
    int pos = poshalf*32 + (lane & 31), pi = pos >> 3, pj = pos & 7;
    int khalf = lane >> 5;
    floatx16 acc;
#pragma unroll
    for (int i = 0; i < 16; ++i) acc[i] = 0.f;
    const uint4* Ah4 = (const uint4*)DAh;
    const uint4* Al4 = (const uint4*)DAl;
#pragma unroll 3
    for (int kstep = 0; kstep < 12; ++kstep) {
        int k0 = kstep*16 + khalf*8;
        int cc = k0 >> 6, yy = (k0 >> 3) & 7;
        int boff = cc*1296 + (4*pi + yy)*36 + 4*pj;
        FragU ah, al, bh, bl;
        ah.u = Ah4[(mhalf*12 + kstep)*64 + lane];
        al.u = Al4[(mhalf*12 + kstep)*64 + lane];
        const uint2* ph = (const uint2*)(xth + boff);
        uint2 h0 = ph[0], h1 = ph[1];
        bh.u = make_uint4(h0.x, h0.y, h1.x, h1.y);
        const uint2* pl = (const uint2*)(xtl + boff);
        uint2 l0 = pl[0], l1 = pl[1];
        bl.u = make_uint4(l0.x, l0.y, l1.x, l1.y);
        acc = __builtin_amdgcn_mfma_f32_32x32x16_bf16(ah.v, bh.v, acc, 0, 0, 0);
        acc = __builtin_amdgcn_mfma_f32_32x32x16_bf16(ah.v, bl.v, acc, 0, 0, 0);
        acc = __builtin_amdgcn_mfma_f32_32x32x16_bf16(al.v, bh.v, acc, 0, 0, 0);
    }
#pragma unroll
    for (int r16 = 0; r16 < 16; ++r16) {
        int row = (r16 & 3) + 8*(r16 >> 2) + 4*khalf;
        ot[(mhalf*32 + row)*65 + pos] = acc[r16];
    }
    __syncthreads();
    // channel-last epilogue: lane = channel -> 256B contiguous stores
    int m = t & 63;
    float* bp = b + (size_t)img*IMGSZ;
    float* up = u + (size_t)img*IMGSZ;
#pragma unroll
    for (int e = 0; e < 16; ++e) {
        int pp = e*4 + (t >> 6);
        int gi = ((i0 + (pp >> 3))*OW + j0 + (pp & 7))*64 + m;
        float v = ot[m*65 + pp];
        bp[gi] = v;
        up[gi] = ETA * v;
    }
}

// One LCA step on a 2-row x 56-col band (channel-last state), FP16 GEMM.
// Interior fast path: terms (T0h, T0l, Tx-masked) hand-inlined inside a
// fully unrolled dp loop -> 9 independent A-loads per kstep batch that the
// compiler pipelines under vmcnt, instead of the runtime-nt term loop's
// serial load->waitcnt->MFMA chain (the R9 latency wall). kstep stays
// unroll-1 to bound liveness (no R7/R8 spill cliff). Edge bands (128 of
// 1792 blocks) keep the runtime term loop with nt=6.
__global__ __launch_bounds__(256, 4) void lca_iter_kernel(
        const float* __restrict__ b, const float* __restrict__ uin,
        float* __restrict__ uout,
        const unsigned short* __restrict__ GAh,
        const unsigned short* __restrict__ GAl,
        float* __restrict__ out, int last) {
    __shared__ __align__(16) unsigned char smem[33280];   // max(29696, 33280)
    unsigned short* at2h = (unsigned short*)smem;         // [rc][swizzled n]
    int blk = blockIdx.x;
    int img = blk / 28, bandi = blk % 28;
    int i0 = bandi*2;
    int t = threadIdx.x;
    const float* ub = uin + (size_t)img*IMGSZ;
    // Phase 1: halo band (4 rows x 58 cols x 64 n) -> soft -> fp16 -> LDS.
    for (int idx = t; idx < 232*16; idx += 256) {
        int chunk = idx >> 4, f4 = idx & 15;
        int p = chunk / 58, q = chunk - 58*p;
        int gi = i0 - 1 + p, gj = q - 1;
        int n0 = f4 << 2;
        float4 v = make_float4(0.f, 0.f, 0.f, 0.f);
        if (gi >= 0 && gi < OH && gj >= 0 && gj < OW)
            v = *(const float4*)(ub + ((gi*OW + gj)*64 + n0));
        ushort4 hv = make_ushort4(f2h(softthr(v.x)), f2h(softthr(v.y)),
                                  f2h(softthr(v.z)), f2h(softthr(v.w)));
        int kg = n0 >> 3;
        int base = chunk*64 + ((kg ^ (chunk & 7)) << 3) + (n0 & 7);
        *(ushort4*)(at2h + base) = hv;
    }
    __syncthreads();
    int lane = t & 63, wave = t >> 6;
    int mhalf = wave & 1, cgrp = wave >> 1;      // cgrp: pj 0..31 / 32..63
    int khalf = lane >> 5, cl = lane & 31;
    int pj = cgrp*32 + cl;
    int pjx = (pj < 56) ? pj : 0;                // clamp invalid columns
    floatx16 acc0, acc1;
#pragma unroll
    for (int i = 0; i < 16; ++i) { acc0[i] = 0.f; acc1[i] = 0.f; }
    const uint4* Gh4 = (const uint4*)GAh;
    const uint4* Gl4 = (const uint4*)GAl;
    const uint4* B4h = (const uint4*)at2h;
    int tbx = (cgrp == 0) ? 3 : 4;               // X boundary table
    unsigned msel = (cl == ((cgrp == 0) ? 0 : 23)) ? 0xFFFFFFFFu : 0u;
    bool edge = (bandi == 0) || (bandi == 27);
    if (!edge) {
        // ---- interior fast path ----
#pragma unroll 1
        for (int dq = 0; dq < 3; ++dq) {
#pragma unroll 1
            for (int kstep = 0; kstep < 4; ++kstep) {
                int kg2 = kstep*2 + khalf;
                FragH B[4];
#pragma unroll
                for (int p = 0; p < 4; ++p) {
                    int rc = p*58 + pjx + dq;
                    B[p].u = B4h[rc*8 + (kg2 ^ (rc & 7))];
                }
#pragma unroll
                for (int dp = 0; dp < 3; ++dp) {
                    int abase = (((3*dp + dq)*2 + mhalf)*4 + kstep)*64 + lane;
                    FragH a0, a1, ax, bm0, bm1;
                    a0.u = Gh4[abase];
                    a1.u = Gl4[abase];
                    ax.u = Gh4[(tbx*9)*512 + abase];
                    bm0.u = make_uint4(B[dp].u.x & msel, B[dp].u.y & msel,
                                       B[dp].u.z & msel, B[dp].u.w & msel);
                    bm1.u = make_uint4(B[dp+1].u.x & msel, B[dp+1].u.y & msel,
                                       B[dp+1].u.z & msel, B[dp+1].u.w & msel);
                    acc0 = __builtin_amdgcn_mfma_f32_32x32x16_f16(a0.v, B[dp].v, acc0, 0,0,0);
                    acc1 = __builtin_amdgcn_mfma_f32_32x32x16_f16(a0.v, B[dp+1].v, acc1, 0,0,0);
                    acc0 = __builtin_amdgcn_mfma_f32_32x32x16_f16(a1.v, B[dp].v, acc0, 0,0,0);
                    acc1 = __builtin_amdgcn_mfma_f32_32x32x16_f16(a1.v, B[dp+1].v, acc1, 0,0,0);
                    acc0 = __builtin_amdgcn_mfma_f32_32x32x16_f16(ax.v, bm0.v, acc0, 0,0,0);
                    acc1 = __builtin_amdgcn_mfma_f32_32x32x16_f16(ax.v, bm1.v, acc1, 0,0,0);
                }
            }
        }
    } else {
        // ---- edge path (bandi 0 or 27): runtime term loop, nt = 6 ----
        int ymask, tby, tbc;
        if (bandi == 0) { ymask = 1; tby = 1; tbc = (cgrp == 0) ? 5 : 6; }
        else            { ymask = 2; tby = 2; tbc = (cgrp == 0) ? 7 : 8; }
#pragma unroll 1
        for (int dq = 0; dq < 3; ++dq) {
#pragma unroll 1
            for (int kstep = 0; kstep < 4; ++kstep) {
                int kg2 = kstep*2 + khalf;
#pragma unroll
                for (int dp = 0; dp < 3; ++dp) {
                    int rc0 = dp*58 + pjx + dq;
                    int rc1 = rc0 + 58;
                    FragH B0, B1;
                    B0.u = B4h[rc0*8 + (kg2 ^ (rc0 & 7))];
                    B1.u = B4h[rc1*8 + (kg2 ^ (rc1 & 7))];
                    for (int tm = 0; tm < 6; ++tm) {
                        int td = (tm < 2) ? 0 : (tm == 2) ? tbx : (tm < 5) ? tby : tbc;
                        const uint4* Ap = ((tm == 1) || (tm == 4)) ? Gl4 : Gh4;
                        bool masked = (tm == 2) || (tm == 5);
                        int am = (tm < 3) ? 3 : ymask;
                        FragH a;
                        a.u = Ap[(((td*9 + 3*dp + dq)*2 + mhalf)*4 + kstep)*64 + lane];
                        if (!masked) {
                            if (am & 1)
                                acc0 = __builtin_amdgcn_mfma_f32_32x32x16_f16(a.v, B0.v, acc0, 0,0,0);
                            if (am & 2)
                                acc1 = __builtin_amdgcn_mfma_f32_32x32x16_f16(a.v, B1.v, acc1, 0,0,0);
                        } else {
                            if (am & 1) {
                                FragH bm;
                                bm.u = make_uint4(B0.u.x & msel, B0.u.y & msel,
                                                  B0.u.z & msel, B0.u.w & msel);
                                acc0 = __builtin_amdgcn_mfma_f32_32x32x16_f16(a.v, bm.v, acc0, 0,0,0);
                            }
                            if (am & 2) {
                                FragH bm;
                                bm.u = make_uint4(B1.u.x & msel, B1.u.y & msel,
                                                  B1.u.z & msel, B1.u.w & msel);
                                acc1 = __builtin_amdgcn_mfma_f32_32x32x16_f16(a.v, bm.v, acc1, 0,0,0);
                            }
                        }
                    }
                }
            }
        }
    }
    __syncthreads();                   // at2 dead; overlay fp32 ot[pos][m]
    float* ot = (float*)smem;          // 128*65*4 = 33280 B
#pragma unroll
    for (int r16 = 0; r16 < 16; ++r16) {
        int row = (r16 & 3) + 8*(r16 >> 2) + 4*khalf;
        int m = mhalf*32 + row;
        ot[pj*65 + m] = acc0[r16];
        ot[(64 + pj)*65 + m] = acc1[r16];
    }
    __syncthreads();
    const float* bp = b + (size_t)img*IMGSZ;
    float* up = uout + (size_t)img*IMGSZ;
#pragma unroll 4
    for (int pass = 0; pass < 28; ++pass) {     // 2*56*64 elems, lane = n
        int idx = pass*256 + t;
        int n = idx & 63;
        int rest = idx >> 6;                    // 0..111
        int pi = (rest >= 56) ? 1 : 0;
        int j = rest - 56*pi;
        int g = ((i0 + pi)*OW + j)*64 + n;
        float uo = ub[g];
        float gram = ot[(pi*64 + j)*65 + n];
        float un = uo + ETA * (bp[g] - uo - gram + softthr(uo));
        if (last) out[(((size_t)img*ATOMS + n)*OH + (i0 + pi))*OW + j] = softthr(un);
        else      up[g] = un;
    }
}

extern "C" void kernel_launch(void* const* d_in, const int* in_sizes, int n_in,
                              void* d_out, int out_size, void* d_ws, size_t ws_size,
                              hipStream_t stream) {
    const float* x = (const float*)d_in[0];
    const float* D = (const float*)d_in[1];
    float* out = (float*)d_out;
    float* ws = (float*)d_ws;
    float* b  = ws;                        // NLAT f32 (channel-last)
    float* u0 = b  + NLAT;                 // NLAT f32
    float* u1 = u0 + NLAT;                 // NLAT f32
    float* DT = u1 + NLAT;                 // 12288 f32
    float* Gf = DT + 12288;                // 81*4096 f32
    unsigned short* GAh = (unsigned short*)(Gf + 331776);
    unsigned short* GAl = GAh + 331776;
    unsigned short* DAh = GAl + 331776;
    unsigned short* DAl = DAh + 12288;
    prep_dt_kernel<<<48, 256, 0, stream>>>(D, DT);
    prep_gram_kernel<<<1296, 256, 0, stream>>>(DT, Gf);
    prep_packg_kernel<<<162, 256, 0, stream>>>(Gf, GAh, GAl);
    prep_packd_kernel<<<6, 256, 0, stream>>>(D, DAh, DAl);
    conv_b_kernel<<<BATCH*49, 256, 0, stream>>>(x, DAh, DAl, b, u0);
    float* uin = u0; float* uo2 = u1;
    for (int it = 0; it < 9; ++it) {       // iterations 2..10 (iter 1 folded)
        int last = (it == 8);
        lca_iter_kernel<<<BATCH*28, 256, 0, stream>>>(b, uin, uo2, GAh, GAl, out, last);
        float* tmp = uin; uin = uo2; uo2 = tmp;
    }
}